// Round 15
// baseline (439.831 us; speedup 1.0000x reference)
//
#include <hip/hip_runtime.h>

// ---------------------------------------------------------------------------
// CausalSelfAttention on MI355X (gfx950), bf16 MFMA pipeline.
// Shapes: B=4, T=2048, C=2048, H=16, D=128. N_qkv=6144.
// d_out = [ out f32 (B,T,C) | k f32 (B,H,T,D) | v f32 (B,H,T,D) ]
// ---------------------------------------------------------------------------

typedef __attribute__((ext_vector_type(4))) float f32x4;
typedef __attribute__((ext_vector_type(8))) __bf16 bf16x8;
typedef __attribute__((ext_vector_type(4))) unsigned short us4;
typedef __attribute__((ext_vector_type(8))) unsigned short us8;

__device__ __forceinline__ unsigned short f2bf(float f) {
  unsigned u = __float_as_uint(f);
  u += 0x7FFFu + ((u >> 16) & 1u);   // round-to-nearest-even
  return (unsigned short)(u >> 16);
}

__device__ __forceinline__ void gl_lds16(const void* g, void* l) {
  __builtin_amdgcn_global_load_lds(
      (const __attribute__((address_space(1))) void*)g,
      (__attribute__((address_space(3))) void*)l, 16, 0, 0);
}

__device__ __forceinline__ f32x4 mfma_bf16(bf16x8 a, bf16x8 b, f32x4 c) {
  return __builtin_amdgcn_mfma_f32_16x16x32_bf16(a, b, c, 0, 0, 0);
}

// ---------------------------------------------------------------------------
// Fused prep kernel: grid-partitioned union of
//   [0,2048)        conv_bf16 of x             (grid-stride, 8 float4/thread)
//   [2048,5120)     transpose W_attn (permuted) 96 x 32 tiles
//   [5120,6144)     transpose W_proj            32 x 32 tiles
//   [6144,6656)     rope cos/sin table
// ---------------------------------------------------------------------------
__global__ __launch_bounds__(256) void prep_kernel(
    const float* __restrict__ x, unsigned short* __restrict__ x_bf,
    const float* __restrict__ W_attn, unsigned short* __restrict__ wt,
    const float* __restrict__ W_proj, unsigned short* __restrict__ wpt,
    float* __restrict__ cos_t, float* __restrict__ sin_t) {
  __shared__ unsigned short tile[64][68];
  const int bid = blockIdx.x;
  const int t = threadIdx.x;

  if (bid < 2048) {  // ---- conv_bf16 ----
    int idx = bid * 256 + t;
    for (; idx < 4194304; idx += 2048 * 256) {
      float4 v = ((const float4*)x)[idx];
      us4 o;
      o[0] = f2bf(v.x); o[1] = f2bf(v.y); o[2] = f2bf(v.z); o[3] = f2bf(v.w);
      ((us4*)x_bf)[idx] = o;
    }
    return;
  }

  const float* in;
  unsigned short* out;
  int R, C, permute, bx, by;
  if (bid < 5120) {         // ---- transpose W_attn ----
    int loc = bid - 2048;
    in = W_attn; out = wt; R = 2048; C = 6144; permute = 1;
    bx = loc % 96; by = loc / 96;
  } else if (bid < 6144) {  // ---- transpose W_proj ----
    int loc = bid - 5120;
    in = W_proj; out = wpt; R = 2048; C = 2048; permute = 0;
    bx = loc & 31; by = loc >> 5;
  } else {                  // ---- rope table ----
    int idx = (bid - 6144) * 256 + t;
    int tt = idx >> 6, i = idx & 63;
    float freq = __expf(-(float)i * 0.14391156831212787f);  // 10000^(-i/64)
    float ang = (float)tt * freq;
    float s, c;
    sincosf(ang, &s, &c);
    cos_t[idx] = c;
    sin_t[idx] = s;
    return;
  }

  const int c0 = bx * 64, r0 = by * 64;
  const int cq = t & 15, rr = t >> 4;
#pragma unroll
  for (int i = 0; i < 4; ++i) {
    int r = rr + i * 16;
    float4 v = *(const float4*)&in[(size_t)(r0 + r) * C + c0 + cq * 4];
    tile[r][cq * 4 + 0] = f2bf(v.x);
    tile[r][cq * 4 + 1] = f2bf(v.y);
    tile[r][cq * 4 + 2] = f2bf(v.z);
    tile[r][cq * 4 + 3] = f2bf(v.w);
  }
  __syncthreads();
#pragma unroll
  for (int ii = 0; ii < 4; ++ii) {
    int c = rr + ii * 16;
    int n = c0 + c;
    int np = n;
    if (permute && n < 4096) {
      int d = n & 127, blk = d >> 5;
      int dd = (blk == 1) ? d + 32 : (blk == 2) ? d - 32 : d;
      np = (n & ~127) | dd;
    }
    us4 o;
#pragma unroll
    for (int jj = 0; jj < 4; ++jj) o[jj] = tile[cq * 4 + jj][c];
    *(us4*)&out[(size_t)np * R + r0 + cq * 4] = o;
  }
}

// ---------------------------------------------------------------------------
// 256x256 8-wave GEMM engine, 4-phase LDS-minimal schedule.
// vs round 14: mid-tile wait corrected WAITV(4)->WAITV(2). Stage issue order
// per tile is [A0,B0,B1,A1]; vmcnt is an in-order queue, so at the mid point
// outstanding = {cur.B1, cur.A1, next.A0, next.B0}: WAITV(2) confirms exactly
// cur.B1/cur.A1 before ph3 reads them (the old WAITV(4) confirmed NOTHING --
// correctness held only because stages were issued a full tile early).
// Entry WAITV(2) confirms cur.A0/cur.B0. No setprio (lockstep waves; m190).
// ---------------------------------------------------------------------------

#define BARR __builtin_amdgcn_s_barrier()
#define WAITV(N) asm volatile("s_waitcnt vmcnt(" #N ")" ::: "memory")

#define STAGE_A_HALF(BUF, T, H)                                                \
  do {                                                                         \
    const int k0_ = (T) * 64;                                                  \
    _Pragma("unroll") for (int i_ = 0; i_ < 2; ++i_) {                         \
      int c_ = i_ * 512 + tid;                                                 \
      int rp_ = c_ >> 3, s_ = c_ & 7;                                          \
      int row_ = (rp_ & 63) + (H) * 64 + (rp_ >> 6) * 128;                     \
      gl_lds16(Ag + (size_t)row_ * 2048 + k0_ + ((s_ ^ (row_ & 7)) << 3),      \
               &As[BUF][row_ * 64 + s_ * 8]);                                  \
    }                                                                          \
  } while (0)

#define STAGE_B_HALF(BUF, T, H)                                                \
  do {                                                                         \
    const int k0_ = (T) * 64;                                                  \
    _Pragma("unroll") for (int i_ = 0; i_ < 2; ++i_) {                         \
      int c_ = i_ * 512 + tid;                                                 \
      int rp_ = c_ >> 3, s_ = c_ & 7;                                          \
      int row_ = (rp_ & 31) + (H) * 32 + (rp_ >> 5) * 64;                      \
      gl_lds16(Bg + (size_t)row_ * 2048 + k0_ + ((s_ ^ (row_ & 7)) << 3),      \
               &Bs[BUF][row_ * 64 + s_ * 8]);                                  \
    }                                                                          \
  } while (0)

#define LDA(mh)                                                                \
  _Pragma("unroll") for (int m2_ = 0; m2_ < 4; ++m2_)                          \
  _Pragma("unroll") for (int kk_ = 0; kk_ < 2; ++kk_) {                        \
    int R_ = wm * 128 + (mh) * 64 + m2_ * 16 + ln;                             \
    av[m2_][kk_] = *(const bf16x8*)&Ab[R_ * 64 +                               \
        (((kk_ * 64 + g * 16) ^ ((R_ & 7) << 4)) >> 1)];                       \
  }

#define LDB2                                                                   \
  _Pragma("unroll") for (int nh_ = 0; nh_ < 2; ++nh_)                          \
  _Pragma("unroll") for (int n2_ = 0; n2_ < 2; ++n2_)                          \
  _Pragma("unroll") for (int kk_ = 0; kk_ < 2; ++kk_) {                        \
    int R_ = wn * 64 + nh_ * 32 + n2_ * 16 + ln;                               \
    bv[nh_ * 2 + n2_][kk_] = *(const bf16x8*)&Bb[R_ * 64 +                     \
        (((kk_ * 64 + g * 16) ^ ((R_ & 7) << 4)) >> 1)];                       \
  }

#define MF16(mh, nh)                                                           \
  do {                                                                         \
    _Pragma("unroll") for (int m2_ = 0; m2_ < 4; ++m2_)                        \
    _Pragma("unroll") for (int n2_ = 0; n2_ < 2; ++n2_)                        \
    _Pragma("unroll") for (int kk_ = 0; kk_ < 2; ++kk_)                        \
      acc[(mh) * 4 + m2_][(nh) * 2 + n2_] = mfma_bf16(                         \
          av[m2_][kk_], bv[(nh) * 2 + n2_][kk_],                               \
          acc[(mh) * 4 + m2_][(nh) * 2 + n2_]);                                \
  } while (0)

#define GEMM_ENGINE_4PH(NT)                                                    \
  STAGE_A_HALF(0, 0, 0); STAGE_B_HALF(0, 0, 0);                                \
  STAGE_B_HALF(0, 0, 1); STAGE_A_HALF(0, 0, 1);                                \
  for (int t = 0; t < (NT); ++t) {                                             \
    const int p_ = t & 1, q_ = p_ ^ 1;                                         \
    const unsigned short* Ab = &As[p_][0];                                     \
    const unsigned short* Bb = &Bs[p_][0];                                     \
    const bool pf_ = (t + 1 < (NT));                                           \
    WAITV(2);   /* confirm cur.A0, cur.B0 (oldest 2 in queue) */               \
    BARR;                                                                      \
    /* ph1: all B + A-half0 reads; stage next.A0 */                            \
    LDB2; LDA(0);                                                              \
    if (pf_) STAGE_A_HALF(q_, t + 1, 0);                                       \
    MF16(0, 0);                                                                \
    /* ph2: stage next.B0 */                                                   \
    if (pf_) STAGE_B_HALF(q_, t + 1, 0);                                       \
    MF16(0, 1);                                                                \
    if (pf_) { WAITV(2); } else { WAITV(0); }  /* confirm cur.B1, cur.A1 */    \
    BARR;                                                                      \
    /* ph3: A-half1 reads; stage next.B1 */                                    \
    LDA(1);                                                                    \
    if (pf_) STAGE_B_HALF(q_, t + 1, 1);                                       \
    MF16(1, 0);                                                                \
    /* ph4: stage next.A1 */                                                   \
    if (pf_) STAGE_A_HALF(q_, t + 1, 1);                                       \
    MF16(1, 1);                                                                \
  }

// ---------------------------------------------------------------------------
// GEMM1: qkv = x @ W_attn + b_attn, fused RoPE epilogue (permuted q/k cols).
// q pre-scaled by (1/sqrt(D))*log2(e) (exp2-domain softmax). v-epilogue
// emits vt bf16 [z][D][T] via LDS transpose (coalesced 256B-segment writes).
// Grid 768; XCD x owns mtiles [4x,4x+4) x all 24 ntiles, n-fastest.
// ---------------------------------------------------------------------------
__global__ __launch_bounds__(512, 2) void gemm_qkv_kernel(
    const unsigned short* __restrict__ xbf, const unsigned short* __restrict__ wt,
    const float* __restrict__ bias, const float* __restrict__ cost,
    const float* __restrict__ sint, float* __restrict__ out_k,
    float* __restrict__ out_v, unsigned short* __restrict__ qbf,
    unsigned short* __restrict__ kbf, unsigned short* __restrict__ vtb) {
  __shared__ __attribute__((aligned(16))) unsigned short As[2][256 * 64];
  __shared__ __attribute__((aligned(16))) unsigned short Bs[2][256 * 64];
  const int tid = threadIdx.x;
  const int wid = tid >> 6, l = tid & 63, g = l >> 4, ln = l & 15;
  const int wm = wid >> 2, wn = wid & 3;
  const int xcd = blockIdx.x & 7, local = blockIdx.x >> 3;  // local in [0,96)
  const int mtile = xcd * 4 + (local & 3);
  const int ntile = local >> 2;
  const unsigned short* Ag = xbf + (size_t)(mtile * 256) * 2048;
  const unsigned short* Bg = wt + (size_t)(ntile * 256) * 2048;

  f32x4 acc[8][4];
#pragma unroll
  for (int i = 0; i < 8; ++i)
#pragma unroll
    for (int j = 0; j < 4; ++j) acc[i][j] = (f32x4){0.f, 0.f, 0.f, 0.f};
  bf16x8 av[4][2], bv[4][2];

  GEMM_ENGINE_4PH(32);

  // ---- epilogue ----
  const int colb = ntile * 256 + wn * 64;   // permuted col base of this wave
  const int p = colb >> 11;                 // block-uniform (ntile-determined)
  const int h = (colb >> 7) & 15;
  const int Mb = mtile * 256 + wm * 128;

  if (p == 2) {  // v: f32 out + bf16 V^T via LDS transpose
    __syncthreads();   // all waves done with main-loop LDS
    unsigned short* reg = (wid < 4) ? &As[0][0] + wid * 8192
                                    : &Bs[0][0] + (wid - 4) * 8192;  // 16KB/wave
    float bvv[4];
#pragma unroll
    for (int nf = 0; nf < 4; ++nf) bvv[nf] = bias[colb + nf * 16 + ln];
    const int dbase = (wn & 1) * 64;
#pragma unroll
    for (int mf = 0; mf < 8; ++mf) {
      int t0 = Mb + mf * 16 + g * 4;
      int bb = t0 >> 11, tt = t0 & 2047;
      size_t base = ((size_t)(bb * 16 + h) * 2048 + tt) * 128;
#pragma unroll
      for (int nf = 0; nf < 4; ++nf) {
        int dl = nf * 16 + ln;                 // wave-local dim 0..63
        us4 pack;
#pragma unroll
        for (int r = 0; r < 4; ++r) {
          float val = acc[mf][nf][r] + bvv[nf];
          out_v[base + (size_t)r * 128 + dbase + dl] = val;
          pack[r] = f2bf(val);
        }
        int byt = (mf * 32 + g * 8) ^ ((dl & 7) << 4);   // swizzled 8B slot
        *(us4*)&reg[dl * 128 + (byt >> 1)] = pack;       // LDS[dl][t] transposed
      }
    }
    asm volatile("s_waitcnt lgkmcnt(0)" ::: "memory");   // wave-private region
    __builtin_amdgcn_sched_barrier(0);
    const size_t vtz = (size_t)((Mb >> 11) * 16 + h) * (128 * 2048);
    const int tbase = (Mb & 2047);           // wave's 128 tokens (wm in Mb)
#pragma unroll
    for (int it = 0; it < 16; ++it) {
      int dl = it * 4 + (l >> 4);
      int byt = ((l & 15) * 16) ^ ((dl & 7) << 4);
      us8 v8 = *(const us8*)&reg[dl * 128 + (byt >> 1)];
      *(us8*)&vtb[vtz + (size_t)(dbase + dl) * 2048 + tbase + (l & 15) * 8] = v8;
    }
  } else {  // q (p==0) or k (p==1): RoPE; partners are acc[.][nf] / acc[.][nf+2]
    // q additionally scaled by 1/sqrt(128) * log2(e) for exp2-domain softmax
    const float sc2 = 0.12751743681128098f;
    const int half32 = (wn & 1) * 32;
    float blo[2], bhi[2];
#pragma unroll
    for (int nf = 0; nf < 2; ++nf) {
      int d_lo = half32 + nf * 16 + ln;
      blo[nf] = bias[p * 2048 + h * 128 + d_lo];
      bhi[nf] = bias[p * 2048 + h * 128 + d_lo + 64];
    }
#pragma unroll
    for (int mf = 0; mf < 8; ++mf)
#pragma unroll
      for (int r = 0; r < 4; ++r) {
        int m = Mb + mf * 16 + g * 4 + r;
        int b = m >> 11, t = m & 2047;
        size_t base = ((size_t)(b * 16 + h) * 2048 + t) * 128;
#pragma unroll
        for (int nf = 0; nf < 2; ++nf) {
          int d_lo = half32 + nf * 16 + ln;
          float cv = cost[t * 64 + d_lo], sv = sint[t * 64 + d_lo];
          float a = acc[mf][nf][r] + blo[nf];
          float bq = acc[mf][nf + 2][r] + bhi[nf];
          float lo = a * cv - bq * sv;
          float hi = bq * cv + a * sv;
          if (p == 0) {
            qbf[base + d_lo] = f2bf(lo * sc2);
            qbf[base + d_lo + 64] = f2bf(hi * sc2);
          } else {
            out_k[base + d_lo] = lo;
            out_k[base + d_lo + 64] = hi;
            kbf[base + d_lo] = f2bf(lo);
            kbf[base + d_lo + 64] = f2bf(hi);
          }
        }
      }
  }
}

// ---------------------------------------------------------------------------
// GEMM2: out = y @ W_proj + b_proj (f32). Grid 256; XCD x owns mtiles
// [4x,4x+4) x all 8 ntiles, n-fastest.
// ---------------------------------------------------------------------------
__global__ __launch_bounds__(512, 2) void gemm_proj_kernel(
    const unsigned short* __restrict__ ybf, const unsigned short* __restrict__ wpt,
    const float* __restrict__ bias, float* __restrict__ out) {
  __shared__ __attribute__((aligned(16))) unsigned short As[2][256 * 64];
  __shared__ __attribute__((aligned(16))) unsigned short Bs[2][256 * 64];
  const int tid = threadIdx.x;
  const int wid = tid >> 6, l = tid & 63, g = l >> 4, ln = l & 15;
  const int wm = wid >> 2, wn = wid & 3;
  const int xcd = blockIdx.x & 7, local = blockIdx.x >> 3;  // local in [0,32)
  const int mtile = xcd * 4 + (local & 3);
  const int ntile = local >> 2;
  const unsigned short* Ag = ybf + (size_t)(mtile * 256) * 2048;
  const unsigned short* Bg = wpt + (size_t)(ntile * 256) * 2048;

  f32x4 acc[8][4];
#pragma unroll
  for (int i = 0; i < 8; ++i)
#pragma unroll
    for (int j = 0; j < 4; ++j) acc[i][j] = (f32x4){0.f, 0.f, 0.f, 0.f};
  bf16x8 av[4][2], bv[4][2];

  GEMM_ENGINE_4PH(32);

  const int n0 = ntile * 256 + wn * 64;
  const int Mb = mtile * 256 + wm * 128;
  float bvv[4];
#pragma unroll
  for (int nf = 0; nf < 4; ++nf) bvv[nf] = bias[n0 + nf * 16 + ln];
#pragma unroll
  for (int mf = 0; mf < 8; ++mf)
#pragma unroll
    for (int r = 0; r < 4; ++r) {
      int m = Mb + mf * 16 + g * 4 + r;
      size_t rb = (size_t)m * 2048 + n0;
#pragma unroll
      for (int nf = 0; nf < 4; ++nf)
        out[rb + nf * 16 + ln] = acc[mf][nf][r] + bvv[nf];
    }
}

// ---------------------------------------------------------------------------
// Flash attention (round-13 structure unchanged: exp2-domain softmax, lazy
// max-reduce, deferred sum-reduce, no setprio). Grid 1024 = z x qp.
// ---------------------------------------------------------------------------
__global__ __launch_bounds__(256, 2) void attn_kernel(
    const unsigned short* __restrict__ qbf, const unsigned short* __restrict__ kbf,
    const unsigned short* __restrict__ vtbf, unsigned short* __restrict__ ybf) {
  __shared__ __attribute__((aligned(16))) unsigned short Ks[2][64 * 128];
  __shared__ __attribute__((aligned(16))) unsigned short Vs[2][128 * 64];
  __shared__ __attribute__((aligned(16))) __bf16 Ps[4][32 * 64];
  const int tid = threadIdx.x;
  const int w = tid >> 6, l = tid & 63, g = l >> 4, ln = l & 15;
  const int bid = blockIdx.x;
  const int z = (bid & 7) * 8 + ((bid >> 3) & 7);
  const int qp = 15 - (bid >> 6);
  const size_t zo = (size_t)z * (2048 * 128);
  const size_t zv = (size_t)z * (128 * 2048);
  const int Q0w = qp * 128 + w * 32;
  const int jn = 2 * qp + 2;
  const int jlw = 2 * qp + (w >> 1);
  __bf16* Pw = Ps[w];

  bf16x8 qv[2][4];
#pragma unroll
  for (int mf = 0; mf < 2; ++mf)
#pragma unroll
    for (int kk = 0; kk < 4; ++kk)
      qv[mf][kk] = *(const bf16x8*)
          &qbf[zo + (size_t)(Q0w + mf * 16 + ln) * 128 + kk * 32 + g * 8];

  f32x4 o[2][8];
#pragma unroll
  for (int mf = 0; mf < 2; ++mf)
#pragma unroll
    for (int nf = 0; nf < 8; ++nf) o[mf][nf] = (f32x4){0.f, 0.f, 0.f, 0.f};
  float mrun[2][4], lpart[2][4];
#pragma unroll
  for (int mf = 0; mf < 2; ++mf)
#pragma unroll
    for (int r = 0; r < 4; ++r) { mrun[mf][r] = -3e38f; lpart[mf][r] = 0.f; }

#define STAGE_KV(J, B)                                                         \
  do {                                                                         \
    const int kv0_ = (J) << 6;                                                 \
    _Pragma("unroll") for (int i_ = 0; i_ < 4; ++i_) {                         \
      int c_ = i_ * 256 + tid;                                                 \
      int r_ = c_ >> 4, s_ = c_ & 15;                                          \
      gl_lds16(kbf + zo + (size_t)(kv0_ + r_) * 128 +                          \
                   (((s_ * 16) ^ ((r_ & 7) << 4)) >> 1),                       \
               &Ks[B][c_ * 8]);                                                \
    }                                                                          \
    _Pragma("unroll") for (int i_ = 0; i_ < 4; ++i_) {                         \
      int c_ = i_ * 256 + tid;                                                 \
      int d_ = c_ >> 3, s_ = c_ & 7;                                           \
      gl_lds16(vtbf + zv + (size_t)d_ * 2048 + kv0_ +                          \
                   (((s_ * 16) ^ ((d_ & 7) << 4)) >> 1),                       \
               &Vs[B][c_ * 8]);                                                \
    }                                                                          \
  } while (0)

  STAGE_KV(0, 0);
  STAGE_KV(1, 1);

  for (int j = 0; j < jn; ++j) {
    if (j + 1 < jn)
      asm volatile("s_waitcnt vmcnt(8)" ::: "memory");
    else
      asm volatile("s_waitcnt vmcnt(0)" ::: "memory");
    __builtin_amdgcn_s_barrier();
    const int bfr = j & 1;
    const unsigned short* Kb = Ks[bfr];
    const unsigned short* Vb = Vs[bfr];

    if (j <= jlw) {
      const int kv0 = j << 6;
      f32x4 s[2][4];
#pragma unroll
      for (int mf = 0; mf < 2; ++mf)
#pragma unroll
        for (int nf = 0; nf < 4; ++nf) s[mf][nf] = (f32x4){0.f, 0.f, 0.f, 0.f};
#pragma unroll
      for (int kk = 0; kk < 4; ++kk) {
        bf16x8 kf[4];
#pragma unroll
        for (int nf = 0; nf < 4; ++nf) {
          int rr = nf * 16 + ln;
          kf[nf] = *(const bf16x8*)
              &Kb[rr * 128 + (((kk * 64 + g * 16) ^ ((rr & 7) << 4)) >> 1)];
        }
#pragma unroll
        for (int mf = 0; mf < 2; ++mf)
#pragma unroll
          for (int nf = 0; nf < 4; ++nf)
            s[mf][nf] = mfma_bf16(qv[mf][kk], kf[nf], s[mf][nf]);
      }

      if (j == jlw) {
#pragma unroll
        for (int mf = 0; mf < 2; ++mf)
#pragma unroll
          for (int nf = 0; nf < 4; ++nf)
#pragma unroll
            for (int r = 0; r < 4; ++r)
              if (kv0 + nf * 16 + ln > Q0w + mf * 16 + g * 4 + r)
                s[mf][nf][r] = -3e38f;
      }

      // in-lane (partial) row max over this lane's 4 cols
      float mxl[2][4];
#pragma unroll
      for (int mf = 0; mf < 2; ++mf)
#pragma unroll
        for (int r = 0; r < 4; ++r)
          mxl[mf][r] = fmaxf(fmaxf(s[mf][0][r], s[mf][1][r]),
                             fmaxf(s[mf][2][r], s[mf][3][r]));

      // lazy defer-max (T13): __any over partial maxes is an equivalent trigger
      float dm = 0.f;
#pragma unroll
      for (int mf = 0; mf < 2; ++mf)
#pragma unroll
        for (int r = 0; r < 4; ++r) dm = fmaxf(dm, mxl[mf][r] - mrun[mf][r]);
      if (__any(dm > 11.5416f)) {   // exp2(11.5416) == e^8
#pragma unroll
        for (int mf = 0; mf < 2; ++mf)
#pragma unroll
          for (int r = 0; r < 4; ++r) {
            float m0 = mxl[mf][r];
            m0 = fmaxf(m0, __shfl_xor(m0, 1));
            m0 = fmaxf(m0, __shfl_xor(m0, 2));
            m0 = fmaxf(m0, __shfl_xor(m0, 4));
            m0 = fmaxf(m0, __shfl_xor(m0, 8));
            float mn = fmaxf(mrun[mf][r], m0);
            float al = exp2f(mrun[mf][r] - mn);
            mrun[mf][r] = mn;
            lpart[mf][r] *= al;
#pragma unroll
            for (int nf = 0; nf < 8; ++nf) o[mf][nf][r] *= al;
          }
      }

      // P = exp2(S - m), per-lane partial sums (reduced once at the end)
#pragma unroll
      for (int mf = 0; mf < 2; ++mf)
#pragma unroll
        for (int r = 0; r < 4; ++r) {
          const float m0 = mrun[mf][r];
          const int row_l = mf * 16 + g * 4 + r;
          float rs = 0.f;
#pragma unroll
          for (int nf = 0; nf < 4; ++nf) {
            float pv = exp2f(s[mf][nf][r] - m0);
            rs += pv;
            int byte = ((nf * 16 + ln) << 1) ^ ((row_l & 7) << 4);
            Pw[row_l * 64 + (byte >> 1)] = (__bf16)pv;
          }
          lpart[mf][r] += rs;
        }

      asm volatile("s_waitcnt lgkmcnt(0)" ::: "memory");
      __builtin_amdgcn_sched_barrier(0);

#pragma unroll
      for (int kk2 = 0; kk2 < 2; ++kk2) {
        bf16x8 pa[2];
#pragma unroll
        for (int mf = 0; mf < 2; ++mf) {
          int pr = mf * 16 + ln;
          int byte = (kk2 * 64 + g * 16) ^ ((pr & 7) << 4);
          pa[mf] = *(const bf16x8*)&Pw[pr * 64 + (byte >> 1)];
        }
#pragma unroll
        for (int nf2 = 0; nf2 < 8; ++nf2) {
          int dr = nf2 * 16 + ln;
          bf16x8 vf = *(const bf16x8*)
              &Vb[dr * 64 + (((kk2 * 64 + g * 16) ^ ((dr & 7) << 4)) >> 1)];
#pragma unroll
          for (int mf = 0; mf < 2; ++mf)
            o[mf][nf2] = mfma_bf16(pa[mf], vf, o[mf][nf2]);
        }
      }
    }

    __builtin_amdgcn_s_barrier();
    __builtin_amdgcn_sched_barrier(0);
    if (j + 2 < jn) STAGE_KV(j + 2, bfr);
  }
#undef STAGE_KV

  // final: one 16-lane sum reduce per row, then normalize + write y
  const int b = z >> 4, h = z & 15;
#pragma unroll
  for (int mf = 0; mf < 2; ++mf)
#pragma unroll
    for (int r = 0; r < 4; ++r) {
      float rs = lpart[mf][r];
      rs += __shfl_xor(rs, 1);
      rs += __shfl_xor(rs, 2);
      rs += __shfl_xor(rs, 4);
      rs += __shfl_xor(rs, 8);
      float inv = 1.f / rs;
      int t = Q0w + mf * 16 + g * 4 + r;
      size_t rb = ((size_t)b * 2048 + t) * 2048 + h * 128;
#pragma unroll
      for (int nf2 = 0; nf2 < 8; ++nf2)
        ybf[rb + nf2 * 16 + ln] = f2bf(o[mf][nf2][r] * inv);
    }
}

// ---------------------------------------------------------------------------
// Launch
// ---------------------------------------------------------------------------
extern "C" void kernel_launch(void* const* d_in, const int* in_sizes, int n_in,
                              void* d_out, int out_size, void* d_ws, size_t ws_size,
                              hipStream_t stream) {
  (void)in_sizes; (void)n_in; (void)out_size; (void)ws_size;
  const float* x      = (const float*)d_in[0];
  const float* W_attn = (const float*)d_in[1];
  const float* b_attn = (const float*)d_in[2];
  const float* W_proj = (const float*)d_in[3];
  const float* b_proj = (const float*)d_in[4];

  float* out   = (float*)d_out;                 // [8192][2048]
  float* out_k = out + 16777216;                // [64][2048][128]
  float* out_v = out + 33554432;                // [64][2048][128]

  char* ws = (char*)d_ws;
  unsigned short* q_bf  = (unsigned short*)(ws + 0);           // 33.5 MB
  unsigned short* k_bf  = (unsigned short*)(ws + 33554432);    // 33.5 MB
  unsigned short* vt_bf = (unsigned short*)(ws + 67108864);    // 33.5 MB
  unsigned short* x_bf  = (unsigned short*)(ws + 100663296);   // 33.5 MB (reused as y2d)
  unsigned short* y2d   = x_bf;                                // x_bf dead after GEMM1
  unsigned short* wt    = (unsigned short*)(ws + 134217728);   // 25.2 MB
  unsigned short* wpt   = (unsigned short*)(ws + 159383552);   // 8.4 MB
  float* cos_t = (float*)(ws + 167772160);                     // 0.5 MB
  float* sin_t = (float*)(ws + 168296448);                     // 0.5 MB

  prep_kernel<<<6656, 256, 0, stream>>>(x, x_bf, W_attn, wt, W_proj, wpt,
                                        cos_t, sin_t);
  gemm_qkv_kernel<<<768, 512, 0, stream>>>(x_bf, wt, b_attn, cos_t, sin_t,
                                           out_k, out_v, q_bf, k_bf, vt_bf);
  attn_kernel<<<1024, 256, 0, stream>>>(q_bf, k_bf, vt_bf, y2d);
  gemm_proj_kernel<<<256, 512, 0, stream>>>(y2d, wpt, b_proj, out);
}

// Round 16
// 416.362 us; speedup vs baseline: 1.0564x; 1.0564x over previous
//
#include <hip/hip_runtime.h>

// ---------------------------------------------------------------------------
// CausalSelfAttention on MI355X (gfx950), bf16 MFMA pipeline.
// Shapes: B=4, T=2048, C=2048, H=16, D=128. N_qkv=6144.
// d_out = [ out f32 (B,T,C) | k f32 (B,H,T,D) | v f32 (B,H,T,D) ]
// ---------------------------------------------------------------------------

typedef __attribute__((ext_vector_type(4))) float f32x4;
typedef __attribute__((ext_vector_type(8))) __bf16 bf16x8;
typedef __attribute__((ext_vector_type(4))) unsigned short us4;
typedef __attribute__((ext_vector_type(8))) unsigned short us8;

__device__ __forceinline__ unsigned short f2bf(float f) {
  unsigned u = __float_as_uint(f);
  u += 0x7FFFu + ((u >> 16) & 1u);   // round-to-nearest-even
  return (unsigned short)(u >> 16);
}

__device__ __forceinline__ void gl_lds16(const void* g, void* l) {
  __builtin_amdgcn_global_load_lds(
      (const __attribute__((address_space(1))) void*)g,
      (__attribute__((address_space(3))) void*)l, 16, 0, 0);
}

__device__ __forceinline__ f32x4 mfma_bf16(bf16x8 a, bf16x8 b, f32x4 c) {
  return __builtin_amdgcn_mfma_f32_16x16x32_bf16(a, b, c, 0, 0, 0);
}

// ---------------------------------------------------------------------------
// Fused prep kernel: grid-partitioned union of
//   [0,2048)        conv_bf16 of x             (grid-stride, 8 float4/thread)
//   [2048,5120)     transpose W_attn (permuted) 96 x 32 tiles
//   [5120,6144)     transpose W_proj            32 x 32 tiles
//   [6144,6656)     rope cos/sin table
// ---------------------------------------------------------------------------
__global__ __launch_bounds__(256) void prep_kernel(
    const float* __restrict__ x, unsigned short* __restrict__ x_bf,
    const float* __restrict__ W_attn, unsigned short* __restrict__ wt,
    const float* __restrict__ W_proj, unsigned short* __restrict__ wpt,
    float* __restrict__ cos_t, float* __restrict__ sin_t) {
  __shared__ unsigned short tile[64][68];
  const int bid = blockIdx.x;
  const int t = threadIdx.x;

  if (bid < 2048) {  // ---- conv_bf16 ----
    int idx = bid * 256 + t;
    for (; idx < 4194304; idx += 2048 * 256) {
      float4 v = ((const float4*)x)[idx];
      us4 o;
      o[0] = f2bf(v.x); o[1] = f2bf(v.y); o[2] = f2bf(v.z); o[3] = f2bf(v.w);
      ((us4*)x_bf)[idx] = o;
    }
    return;
  }

  const float* in;
  unsigned short* out;
  int R, C, permute, bx, by;
  if (bid < 5120) {         // ---- transpose W_attn ----
    int loc = bid - 2048;
    in = W_attn; out = wt; R = 2048; C = 6144; permute = 1;
    bx = loc % 96; by = loc / 96;
  } else if (bid < 6144) {  // ---- transpose W_proj ----
    int loc = bid - 5120;
    in = W_proj; out = wpt; R = 2048; C = 2048; permute = 0;
    bx = loc & 31; by = loc >> 5;
  } else {                  // ---- rope table ----
    int idx = (bid - 6144) * 256 + t;
    int tt = idx >> 6, i = idx & 63;
    float freq = __expf(-(float)i * 0.14391156831212787f);  // 10000^(-i/64)
    float ang = (float)tt * freq;
    float s, c;
    sincosf(ang, &s, &c);
    cos_t[idx] = c;
    sin_t[idx] = s;
    return;
  }

  const int c0 = bx * 64, r0 = by * 64;
  const int cq = t & 15, rr = t >> 4;
#pragma unroll
  for (int i = 0; i < 4; ++i) {
    int r = rr + i * 16;
    float4 v = *(const float4*)&in[(size_t)(r0 + r) * C + c0 + cq * 4];
    tile[r][cq * 4 + 0] = f2bf(v.x);
    tile[r][cq * 4 + 1] = f2bf(v.y);
    tile[r][cq * 4 + 2] = f2bf(v.z);
    tile[r][cq * 4 + 3] = f2bf(v.w);
  }
  __syncthreads();
#pragma unroll
  for (int ii = 0; ii < 4; ++ii) {
    int c = rr + ii * 16;
    int n = c0 + c;
    int np = n;
    if (permute && n < 4096) {
      int d = n & 127, blk = d >> 5;
      int dd = (blk == 1) ? d + 32 : (blk == 2) ? d - 32 : d;
      np = (n & ~127) | dd;
    }
    us4 o;
#pragma unroll
    for (int jj = 0; jj < 4; ++jj) o[jj] = tile[cq * 4 + jj][c];
    *(us4*)&out[(size_t)np * R + r0 + cq * 4] = o;
  }
}

// ---------------------------------------------------------------------------
// 256x256 8-wave GEMM engine, 4-phase LDS-minimal schedule.
// Best-measured config (round 6/14: 202-206us) restored: setprio(1) around
// MFMA clusters (our staggered 2-barrier loop IS role-split -- r15 A/B showed
// removing it costs ~24us). Waits now SOUND (vs r14's timing-lucky ones):
// stage issue order per tile is [A0,B0,B1,A1]; ph1's LDB2 reads BOTH B
// halves, so entry WAITV(1) confirms oldest 3 = {A0,B0,B1}; mid outstanding
// = {A1, next.A0, next.B0} so WAITV(2) confirms A1 before ph3 reads it.
// Each wait targets loads issued >=2 phases earlier -> ~no stall.
// ---------------------------------------------------------------------------

#define BARR __builtin_amdgcn_s_barrier()
#define WAITV(N) asm volatile("s_waitcnt vmcnt(" #N ")" ::: "memory")

#define STAGE_A_HALF(BUF, T, H)                                                \
  do {                                                                         \
    const int k0_ = (T) * 64;                                                  \
    _Pragma("unroll") for (int i_ = 0; i_ < 2; ++i_) {                         \
      int c_ = i_ * 512 + tid;                                                 \
      int rp_ = c_ >> 3, s_ = c_ & 7;                                          \
      int row_ = (rp_ & 63) + (H) * 64 + (rp_ >> 6) * 128;                     \
      gl_lds16(Ag + (size_t)row_ * 2048 + k0_ + ((s_ ^ (row_ & 7)) << 3),      \
               &As[BUF][row_ * 64 + s_ * 8]);                                  \
    }                                                                          \
  } while (0)

#define STAGE_B_HALF(BUF, T, H)                                                \
  do {                                                                         \
    const int k0_ = (T) * 64;                                                  \
    _Pragma("unroll") for (int i_ = 0; i_ < 2; ++i_) {                         \
      int c_ = i_ * 512 + tid;                                                 \
      int rp_ = c_ >> 3, s_ = c_ & 7;                                          \
      int row_ = (rp_ & 31) + (H) * 32 + (rp_ >> 5) * 64;                      \
      gl_lds16(Bg + (size_t)row_ * 2048 + k0_ + ((s_ ^ (row_ & 7)) << 3),      \
               &Bs[BUF][row_ * 64 + s_ * 8]);                                  \
    }                                                                          \
  } while (0)

#define LDA(mh)                                                                \
  _Pragma("unroll") for (int m2_ = 0; m2_ < 4; ++m2_)                          \
  _Pragma("unroll") for (int kk_ = 0; kk_ < 2; ++kk_) {                        \
    int R_ = wm * 128 + (mh) * 64 + m2_ * 16 + ln;                             \
    av[m2_][kk_] = *(const bf16x8*)&Ab[R_ * 64 +                               \
        (((kk_ * 64 + g * 16) ^ ((R_ & 7) << 4)) >> 1)];                       \
  }

#define LDB2                                                                   \
  _Pragma("unroll") for (int nh_ = 0; nh_ < 2; ++nh_)                          \
  _Pragma("unroll") for (int n2_ = 0; n2_ < 2; ++n2_)                          \
  _Pragma("unroll") for (int kk_ = 0; kk_ < 2; ++kk_) {                        \
    int R_ = wn * 64 + nh_ * 32 + n2_ * 16 + ln;                               \
    bv[nh_ * 2 + n2_][kk_] = *(const bf16x8*)&Bb[R_ * 64 +                     \
        (((kk_ * 64 + g * 16) ^ ((R_ & 7) << 4)) >> 1)];                       \
  }

#define MF16(mh, nh)                                                           \
  do {                                                                         \
    __builtin_amdgcn_s_setprio(1);                                             \
    _Pragma("unroll") for (int m2_ = 0; m2_ < 4; ++m2_)                        \
    _Pragma("unroll") for (int n2_ = 0; n2_ < 2; ++n2_)                        \
    _Pragma("unroll") for (int kk_ = 0; kk_ < 2; ++kk_)                        \
      acc[(mh) * 4 + m2_][(nh) * 2 + n2_] = mfma_bf16(                         \
          av[m2_][kk_], bv[(nh) * 2 + n2_][kk_],                               \
          acc[(mh) * 4 + m2_][(nh) * 2 + n2_]);                                \
    __builtin_amdgcn_s_setprio(0);                                             \
  } while (0)

#define GEMM_ENGINE_4PH(NT)                                                    \
  STAGE_A_HALF(0, 0, 0); STAGE_B_HALF(0, 0, 0);                                \
  STAGE_B_HALF(0, 0, 1); STAGE_A_HALF(0, 0, 1);                                \
  for (int t = 0; t < (NT); ++t) {                                             \
    const int p_ = t & 1, q_ = p_ ^ 1;                                         \
    const unsigned short* Ab = &As[p_][0];                                     \
    const unsigned short* Bb = &Bs[p_][0];                                     \
    const bool pf_ = (t + 1 < (NT));                                           \
    WAITV(1);   /* confirm cur.A0, cur.B0, cur.B1 (oldest 3) */                \
    BARR;                                                                      \
    /* ph1: all B + A-half0 reads; stage next.A0 */                            \
    LDB2; LDA(0);                                                              \
    if (pf_) STAGE_A_HALF(q_, t + 1, 0);                                       \
    MF16(0, 0);                                                                \
    /* ph2: stage next.B0 */                                                   \
    if (pf_) STAGE_B_HALF(q_, t + 1, 0);                                       \
    MF16(0, 1);                                                                \
    if (pf_) { WAITV(2); } else { WAITV(0); }  /* confirm cur.A1 */            \
    BARR;                                                                      \
    /* ph3: A-half1 reads; stage next.B1 */                                    \
    LDA(1);                                                                    \
    if (pf_) STAGE_B_HALF(q_, t + 1, 1);                                       \
    MF16(1, 0);                                                                \
    /* ph4: stage next.A1 */                                                   \
    if (pf_) STAGE_A_HALF(q_, t + 1, 1);                                       \
    MF16(1, 1);                                                                \
  }

// ---------------------------------------------------------------------------
// GEMM1: qkv = x @ W_attn + b_attn, fused RoPE epilogue (permuted q/k cols).
// q pre-scaled by (1/sqrt(D))*log2(e) (exp2-domain softmax). v-epilogue
// emits vt bf16 [z][D][T] via LDS transpose (coalesced 256B-segment writes).
// Grid 768; XCD x owns mtiles [4x,4x+4) x all 24 ntiles, n-fastest.
// ---------------------------------------------------------------------------
__global__ __launch_bounds__(512, 2) void gemm_qkv_kernel(
    const unsigned short* __restrict__ xbf, const unsigned short* __restrict__ wt,
    const float* __restrict__ bias, const float* __restrict__ cost,
    const float* __restrict__ sint, float* __restrict__ out_k,
    float* __restrict__ out_v, unsigned short* __restrict__ qbf,
    unsigned short* __restrict__ kbf, unsigned short* __restrict__ vtb) {
  __shared__ __attribute__((aligned(16))) unsigned short As[2][256 * 64];
  __shared__ __attribute__((aligned(16))) unsigned short Bs[2][256 * 64];
  const int tid = threadIdx.x;
  const int wid = tid >> 6, l = tid & 63, g = l >> 4, ln = l & 15;
  const int wm = wid >> 2, wn = wid & 3;
  const int xcd = blockIdx.x & 7, local = blockIdx.x >> 3;  // local in [0,96)
  const int mtile = xcd * 4 + (local & 3);
  const int ntile = local >> 2;
  const unsigned short* Ag = xbf + (size_t)(mtile * 256) * 2048;
  const unsigned short* Bg = wt + (size_t)(ntile * 256) * 2048;

  f32x4 acc[8][4];
#pragma unroll
  for (int i = 0; i < 8; ++i)
#pragma unroll
    for (int j = 0; j < 4; ++j) acc[i][j] = (f32x4){0.f, 0.f, 0.f, 0.f};
  bf16x8 av[4][2], bv[4][2];

  GEMM_ENGINE_4PH(32);

  // ---- epilogue ----
  const int colb = ntile * 256 + wn * 64;   // permuted col base of this wave
  const int p = colb >> 11;                 // block-uniform (ntile-determined)
  const int h = (colb >> 7) & 15;
  const int Mb = mtile * 256 + wm * 128;

  if (p == 2) {  // v: f32 out + bf16 V^T via LDS transpose
    __syncthreads();   // all waves done with main-loop LDS
    unsigned short* reg = (wid < 4) ? &As[0][0] + wid * 8192
                                    : &Bs[0][0] + (wid - 4) * 8192;  // 16KB/wave
    float bvv[4];
#pragma unroll
    for (int nf = 0; nf < 4; ++nf) bvv[nf] = bias[colb + nf * 16 + ln];
    const int dbase = (wn & 1) * 64;
#pragma unroll
    for (int mf = 0; mf < 8; ++mf) {
      int t0 = Mb + mf * 16 + g * 4;
      int bb = t0 >> 11, tt = t0 & 2047;
      size_t base = ((size_t)(bb * 16 + h) * 2048 + tt) * 128;
#pragma unroll
      for (int nf = 0; nf < 4; ++nf) {
        int dl = nf * 16 + ln;                 // wave-local dim 0..63
        us4 pack;
#pragma unroll
        for (int r = 0; r < 4; ++r) {
          float val = acc[mf][nf][r] + bvv[nf];
          out_v[base + (size_t)r * 128 + dbase + dl] = val;
          pack[r] = f2bf(val);
        }
        int byt = (mf * 32 + g * 8) ^ ((dl & 7) << 4);   // swizzled 8B slot
        *(us4*)&reg[dl * 128 + (byt >> 1)] = pack;       // LDS[dl][t] transposed
      }
    }
    asm volatile("s_waitcnt lgkmcnt(0)" ::: "memory");   // wave-private region
    __builtin_amdgcn_sched_barrier(0);
    const size_t vtz = (size_t)((Mb >> 11) * 16 + h) * (128 * 2048);
    const int tbase = (Mb & 2047);           // wave's 128 tokens (wm in Mb)
#pragma unroll
    for (int it = 0; it < 16; ++it) {
      int dl = it * 4 + (l >> 4);
      int byt = ((l & 15) * 16) ^ ((dl & 7) << 4);
      us8 v8 = *(const us8*)&reg[dl * 128 + (byt >> 1)];
      *(us8*)&vtb[vtz + (size_t)(dbase + dl) * 2048 + tbase + (l & 15) * 8] = v8;
    }
  } else {  // q (p==0) or k (p==1): RoPE; partners are acc[.][nf] / acc[.][nf+2]
    // q additionally scaled by 1/sqrt(128) * log2(e) for exp2-domain softmax
    const float sc2 = 0.12751743681128098f;
    const int half32 = (wn & 1) * 32;
    float blo[2], bhi[2];
#pragma unroll
    for (int nf = 0; nf < 2; ++nf) {
      int d_lo = half32 + nf * 16 + ln;
      blo[nf] = bias[p * 2048 + h * 128 + d_lo];
      bhi[nf] = bias[p * 2048 + h * 128 + d_lo + 64];
    }
#pragma unroll
    for (int mf = 0; mf < 8; ++mf)
#pragma unroll
      for (int r = 0; r < 4; ++r) {
        int m = Mb + mf * 16 + g * 4 + r;
        int b = m >> 11, t = m & 2047;
        size_t base = ((size_t)(b * 16 + h) * 2048 + t) * 128;
#pragma unroll
        for (int nf = 0; nf < 2; ++nf) {
          int d_lo = half32 + nf * 16 + ln;
          float cv = cost[t * 64 + d_lo], sv = sint[t * 64 + d_lo];
          float a = acc[mf][nf][r] + blo[nf];
          float bq = acc[mf][nf + 2][r] + bhi[nf];
          float lo = a * cv - bq * sv;
          float hi = bq * cv + a * sv;
          if (p == 0) {
            qbf[base + d_lo] = f2bf(lo * sc2);
            qbf[base + d_lo + 64] = f2bf(hi * sc2);
          } else {
            out_k[base + d_lo] = lo;
            out_k[base + d_lo + 64] = hi;
            kbf[base + d_lo] = f2bf(lo);
            kbf[base + d_lo + 64] = f2bf(hi);
          }
        }
      }
  }
}

// ---------------------------------------------------------------------------
// GEMM2: out = y @ W_proj + b_proj (f32). Grid 256; XCD x owns mtiles
// [4x,4x+4) x all 8 ntiles, n-fastest.
// ---------------------------------------------------------------------------
__global__ __launch_bounds__(512, 2) void gemm_proj_kernel(
    const unsigned short* __restrict__ ybf, const unsigned short* __restrict__ wpt,
    const float* __restrict__ bias, float* __restrict__ out) {
  __shared__ __attribute__((aligned(16))) unsigned short As[2][256 * 64];
  __shared__ __attribute__((aligned(16))) unsigned short Bs[2][256 * 64];
  const int tid = threadIdx.x;
  const int wid = tid >> 6, l = tid & 63, g = l >> 4, ln = l & 15;
  const int wm = wid >> 2, wn = wid & 3;
  const int xcd = blockIdx.x & 7, local = blockIdx.x >> 3;  // local in [0,32)
  const int mtile = xcd * 4 + (local & 3);
  const int ntile = local >> 2;
  const unsigned short* Ag = ybf + (size_t)(mtile * 256) * 2048;
  const unsigned short* Bg = wpt + (size_t)(ntile * 256) * 2048;

  f32x4 acc[8][4];
#pragma unroll
  for (int i = 0; i < 8; ++i)
#pragma unroll
    for (int j = 0; j < 4; ++j) acc[i][j] = (f32x4){0.f, 0.f, 0.f, 0.f};
  bf16x8 av[4][2], bv[4][2];

  GEMM_ENGINE_4PH(32);

  const int n0 = ntile * 256 + wn * 64;
  const int Mb = mtile * 256 + wm * 128;
  float bvv[4];
#pragma unroll
  for (int nf = 0; nf < 4; ++nf) bvv[nf] = bias[n0 + nf * 16 + ln];
#pragma unroll
  for (int mf = 0; mf < 8; ++mf)
#pragma unroll
    for (int r = 0; r < 4; ++r) {
      int m = Mb + mf * 16 + g * 4 + r;
      size_t rb = (size_t)m * 2048 + n0;
#pragma unroll
      for (int nf = 0; nf < 4; ++nf)
        out[rb + nf * 16 + ln] = acc[mf][nf][r] + bvv[nf];
    }
}

// ---------------------------------------------------------------------------
// Flash attention (round-13 structure unchanged: exp2-domain softmax, lazy
// max-reduce, deferred sum-reduce, no setprio). Grid 1024 = z x qp.
// ---------------------------------------------------------------------------
__global__ __launch_bounds__(256, 2) void attn_kernel(
    const unsigned short* __restrict__ qbf, const unsigned short* __restrict__ kbf,
    const unsigned short* __restrict__ vtbf, unsigned short* __restrict__ ybf) {
  __shared__ __attribute__((aligned(16))) unsigned short Ks[2][64 * 128];
  __shared__ __attribute__((aligned(16))) unsigned short Vs[2][128 * 64];
  __shared__ __attribute__((aligned(16))) __bf16 Ps[4][32 * 64];
  const int tid = threadIdx.x;
  const int w = tid >> 6, l = tid & 63, g = l >> 4, ln = l & 15;
  const int bid = blockIdx.x;
  const int z = (bid & 7) * 8 + ((bid >> 3) & 7);
  const int qp = 15 - (bid >> 6);
  const size_t zo = (size_t)z * (2048 * 128);
  const size_t zv = (size_t)z * (128 * 2048);
  const int Q0w = qp * 128 + w * 32;
  const int jn = 2 * qp + 2;
  const int jlw = 2 * qp + (w >> 1);
  __bf16* Pw = Ps[w];

  bf16x8 qv[2][4];
#pragma unroll
  for (int mf = 0; mf < 2; ++mf)
#pragma unroll
    for (int kk = 0; kk < 4; ++kk)
      qv[mf][kk] = *(const bf16x8*)
          &qbf[zo + (size_t)(Q0w + mf * 16 + ln) * 128 + kk * 32 + g * 8];

  f32x4 o[2][8];
#pragma unroll
  for (int mf = 0; mf < 2; ++mf)
#pragma unroll
    for (int nf = 0; nf < 8; ++nf) o[mf][nf] = (f32x4){0.f, 0.f, 0.f, 0.f};
  float mrun[2][4], lpart[2][4];
#pragma unroll
  for (int mf = 0; mf < 2; ++mf)
#pragma unroll
    for (int r = 0; r < 4; ++r) { mrun[mf][r] = -3e38f; lpart[mf][r] = 0.f; }

#define STAGE_KV(J, B)                                                         \
  do {                                                                         \
    const int kv0_ = (J) << 6;                                                 \
    _Pragma("unroll") for (int i_ = 0; i_ < 4; ++i_) {                         \
      int c_ = i_ * 256 + tid;                                                 \
      int r_ = c_ >> 4, s_ = c_ & 15;                                          \
      gl_lds16(kbf + zo + (size_t)(kv0_ + r_) * 128 +                          \
                   (((s_ * 16) ^ ((r_ & 7) << 4)) >> 1),                       \
               &Ks[B][c_ * 8]);                                                \
    }                                                                          \
    _Pragma("unroll") for (int i_ = 0; i_ < 4; ++i_) {                         \
      int c_ = i_ * 256 + tid;                                                 \
      int d_ = c_ >> 3, s_ = c_ & 7;                                           \
      gl_lds16(vtbf + zv + (size_t)d_ * 2048 + kv0_ +                          \
                   (((s_ * 16) ^ ((d_ & 7) << 4)) >> 1),                       \
               &Vs[B][c_ * 8]);                                                \
    }                                                                          \
  } while (0)

  STAGE_KV(0, 0);
  STAGE_KV(1, 1);

  for (int j = 0; j < jn; ++j) {
    if (j + 1 < jn)
      asm volatile("s_waitcnt vmcnt(8)" ::: "memory");
    else
      asm volatile("s_waitcnt vmcnt(0)" ::: "memory");
    __builtin_amdgcn_s_barrier();
    const int bfr = j & 1;
    const unsigned short* Kb = Ks[bfr];
    const unsigned short* Vb = Vs[bfr];

    if (j <= jlw) {
      const int kv0 = j << 6;
      f32x4 s[2][4];
#pragma unroll
      for (int mf = 0; mf < 2; ++mf)
#pragma unroll
        for (int nf = 0; nf < 4; ++nf) s[mf][nf] = (f32x4){0.f, 0.f, 0.f, 0.f};
#pragma unroll
      for (int kk = 0; kk < 4; ++kk) {
        bf16x8 kf[4];
#pragma unroll
        for (int nf = 0; nf < 4; ++nf) {
          int rr = nf * 16 + ln;
          kf[nf] = *(const bf16x8*)
              &Kb[rr * 128 + (((kk * 64 + g * 16) ^ ((rr & 7) << 4)) >> 1)];
        }
#pragma unroll
        for (int mf = 0; mf < 2; ++mf)
#pragma unroll
          for (int nf = 0; nf < 4; ++nf)
            s[mf][nf] = mfma_bf16(qv[mf][kk], kf[nf], s[mf][nf]);
      }

      if (j == jlw) {
#pragma unroll
        for (int mf = 0; mf < 2; ++mf)
#pragma unroll
          for (int nf = 0; nf < 4; ++nf)
#pragma unroll
            for (int r = 0; r < 4; ++r)
              if (kv0 + nf * 16 + ln > Q0w + mf * 16 + g * 4 + r)
                s[mf][nf][r] = -3e38f;
      }

      // in-lane (partial) row max over this lane's 4 cols
      float mxl[2][4];
#pragma unroll
      for (int mf = 0; mf < 2; ++mf)
#pragma unroll
        for (int r = 0; r < 4; ++r)
          mxl[mf][r] = fmaxf(fmaxf(s[mf][0][r], s[mf][1][r]),
                             fmaxf(s[mf][2][r], s[mf][3][r]));

      // lazy defer-max (T13): __any over partial maxes is an equivalent trigger
      float dm = 0.f;
#pragma unroll
      for (int mf = 0; mf < 2; ++mf)
#pragma unroll
        for (int r = 0; r < 4; ++r) dm = fmaxf(dm, mxl[mf][r] - mrun[mf][r]);
      if (__any(dm > 11.5416f)) {   // exp2(11.5416) == e^8
#pragma unroll
        for (int mf = 0; mf < 2; ++mf)
#pragma unroll
          for (int r = 0; r < 4; ++r) {
            float m0 = mxl[mf][r];
            m0 = fmaxf(m0, __shfl_xor(m0, 1));
            m0 = fmaxf(m0, __shfl_xor(m0, 2));
            m0 = fmaxf(m0, __shfl_xor(m0, 4));
            m0 = fmaxf(m0, __shfl_xor(m0, 8));
            float mn = fmaxf(mrun[mf][r], m0);
            float al = exp2f(mrun[mf][r] - mn);
            mrun[mf][r] = mn;
            lpart[mf][r] *= al;
#pragma unroll
            for (int nf = 0; nf < 8; ++nf) o[mf][nf][r] *= al;
          }
      }

      // P = exp2(S - m), per-lane partial sums (reduced once at the end)
#pragma unroll
      for (int mf = 0; mf < 2; ++mf)
#pragma unroll
        for (int r = 0; r < 4; ++r) {
          const float m0 = mrun[mf][r];
          const int row_l = mf * 16 + g * 4 + r;
          float rs = 0.f;
#pragma unroll
          for (int nf = 0; nf < 4; ++nf) {
            float pv = exp2f(s[mf][nf][r] - m0);
            rs += pv;
            int byte = ((nf * 16 + ln) << 1) ^ ((row_l & 7) << 4);
            Pw[row_l * 64 + (byte >> 1)] = (__bf16)pv;
          }
          lpart[mf][r] += rs;
        }

      asm volatile("s_waitcnt lgkmcnt(0)" ::: "memory");
      __builtin_amdgcn_sched_barrier(0);

#pragma unroll
      for (int kk2 = 0; kk2 < 2; ++kk2) {
        bf16x8 pa[2];
#pragma unroll
        for (int mf = 0; mf < 2; ++mf) {
          int pr = mf * 16 + ln;
          int byte = (kk2 * 64 + g * 16) ^ ((pr & 7) << 4);
          pa[mf] = *(const bf16x8*)&Pw[pr * 64 + (byte >> 1)];
        }
#pragma unroll
        for (int nf2 = 0; nf2 < 8; ++nf2) {
          int dr = nf2 * 16 + ln;
          bf16x8 vf = *(const bf16x8*)
              &Vb[dr * 64 + (((kk2 * 64 + g * 16) ^ ((dr & 7) << 4)) >> 1)];
#pragma unroll
          for (int mf = 0; mf < 2; ++mf)
            o[mf][nf2] = mfma_bf16(pa[mf], vf, o[mf][nf2]);
        }
      }
    }

    __builtin_amdgcn_s_barrier();
    __builtin_amdgcn_sched_barrier(0);
    if (j + 2 < jn) STAGE_KV(j + 2, bfr);
  }
#undef STAGE_KV

  // final: one 16-lane sum reduce per row, then normalize + write y
  const int b = z >> 4, h = z & 15;
#pragma unroll
  for (int mf = 0; mf < 2; ++mf)
#pragma unroll
    for (int r = 0; r < 4; ++r) {
      float rs = lpart[mf][r];
      rs += __shfl_xor(rs, 1);
      rs += __shfl_xor(rs, 2);
      rs += __shfl_xor(rs, 4);
      rs += __shfl_xor(rs, 8);
      float inv = 1.f / rs;
      int t = Q0w + mf * 16 + g * 4 + r;
      size_t rb = ((size_t)b * 2048 + t) * 2048 + h * 128;
#pragma unroll
      for (int nf2 = 0; nf2 < 8; ++nf2)
        ybf[rb + nf2 * 16 + ln] = f2bf(o[mf][nf2][r] * inv);
    }
}

// ---------------------------------------------------------------------------
// Launch
// ---------------------------------------------------------------------------
extern "C" void kernel_launch(void* const* d_in, const int* in_sizes, int n_in,
                              void* d_out, int out_size, void* d_ws, size_t ws_size,
                              hipStream_t stream) {
  (void)in_sizes; (void)n_in; (void)out_size; (void)ws_size;
  const float* x      = (const float*)d_in[0];
  const float* W_attn = (const float*)d_in[1];
  const float* b_attn = (const float*)d_in[2];
  const float* W_proj = (const float*)d_in[3];
  const float* b_proj = (const float*)d_in[4];

  float* out   = (float*)d_out;                 // [8192][2048]
  float* out_k = out + 16777216;                // [64][2048][128]
  float* out_v = out + 33554432;                // [64][2048][128]

  char* ws = (char*)d_ws;
  unsigned short* q_bf  = (unsigned short*)(ws + 0);           // 33.5 MB
  unsigned short* k_bf  = (unsigned short*)(ws + 33554432);    // 33.5 MB
  unsigned short* vt_bf = (unsigned short*)(ws + 67108864);    // 33.5 MB
  unsigned short* x_bf  = (unsigned short*)(ws + 100663296);   // 33.5 MB (reused as y2d)
  unsigned short* y2d   = x_bf;                                // x_bf dead after GEMM1
  unsigned short* wt    = (unsigned short*)(ws + 134217728);   // 25.2 MB
  unsigned short* wpt   = (unsigned short*)(ws + 159383552);   // 8.4 MB
  float* cos_t = (float*)(ws + 167772160);                     // 0.5 MB
  float* sin_t = (float*)(ws + 168296448);                     // 0.5 MB

  prep_kernel<<<6656, 256, 0, stream>>>(x, x_bf, W_attn, wt, W_proj, wpt,
                                        cos_t, sin_t);
  gemm_qkv_kernel<<<768, 512, 0, stream>>>(x_bf, wt, b_attn, cos_t, sin_t,
                                           out_k, out_v, q_bf, k_bf, vt_bf);
  attn_kernel<<<1024, 256, 0, stream>>>(q_bf, k_bf, vt_bf, y2d);
  gemm_proj_kernel<<<256, 512, 0, stream>>>(y2d, wpt, b_proj, out);
}

// Round 17
// 411.548 us; speedup vs baseline: 1.0687x; 1.0117x over previous
//
#include <hip/hip_runtime.h>

// ---------------------------------------------------------------------------
// CausalSelfAttention on MI355X (gfx950), bf16 MFMA pipeline.
// Shapes: B=4, T=2048, C=2048, H=16, D=128. N_qkv=6144.
// d_out = [ out f32 (B,T,C) | k f32 (B,H,T,D) | v f32 (B,H,T,D) ]
// ---------------------------------------------------------------------------

typedef __attribute__((ext_vector_type(4))) float f32x4;
typedef __attribute__((ext_vector_type(8))) __bf16 bf16x8;
typedef __attribute__((ext_vector_type(4))) unsigned short us4;
typedef __attribute__((ext_vector_type(8))) unsigned short us8;

__device__ __forceinline__ unsigned short f2bf(float f) {
  unsigned u = __float_as_uint(f);
  u += 0x7FFFu + ((u >> 16) & 1u);   // round-to-nearest-even
  return (unsigned short)(u >> 16);
}

__device__ __forceinline__ void gl_lds16(const void* g, void* l) {
  __builtin_amdgcn_global_load_lds(
      (const __attribute__((address_space(1))) void*)g,
      (__attribute__((address_space(3))) void*)l, 16, 0, 0);
}

__device__ __forceinline__ f32x4 mfma_bf16(bf16x8 a, bf16x8 b, f32x4 c) {
  return __builtin_amdgcn_mfma_f32_16x16x32_bf16(a, b, c, 0, 0, 0);
}

// ---------------------------------------------------------------------------
// Fused prep kernel: grid-partitioned union of
//   [0,2048)        conv_bf16 of x             (grid-stride, 8 float4/thread)
//   [2048,5120)     transpose W_attn (permuted) 96 x 32 tiles
//   [5120,6144)     transpose W_proj            32 x 32 tiles
//   [6144,6656)     rope cos/sin table
// ---------------------------------------------------------------------------
__global__ __launch_bounds__(256) void prep_kernel(
    const float* __restrict__ x, unsigned short* __restrict__ x_bf,
    const float* __restrict__ W_attn, unsigned short* __restrict__ wt,
    const float* __restrict__ W_proj, unsigned short* __restrict__ wpt,
    float* __restrict__ cos_t, float* __restrict__ sin_t) {
  __shared__ unsigned short tile[64][68];
  const int bid = blockIdx.x;
  const int t = threadIdx.x;

  if (bid < 2048) {  // ---- conv_bf16 ----
    int idx = bid * 256 + t;
    for (; idx < 4194304; idx += 2048 * 256) {
      float4 v = ((const float4*)x)[idx];
      us4 o;
      o[0] = f2bf(v.x); o[1] = f2bf(v.y); o[2] = f2bf(v.z); o[3] = f2bf(v.w);
      ((us4*)x_bf)[idx] = o;
    }
    return;
  }

  const float* in;
  unsigned short* out;
  int R, C, permute, bx, by;
  if (bid < 5120) {         // ---- transpose W_attn ----
    int loc = bid - 2048;
    in = W_attn; out = wt; R = 2048; C = 6144; permute = 1;
    bx = loc % 96; by = loc / 96;
  } else if (bid < 6144) {  // ---- transpose W_proj ----
    int loc = bid - 5120;
    in = W_proj; out = wpt; R = 2048; C = 2048; permute = 0;
    bx = loc & 31; by = loc >> 5;
  } else {                  // ---- rope table ----
    int idx = (bid - 6144) * 256 + t;
    int tt = idx >> 6, i = idx & 63;
    float freq = __expf(-(float)i * 0.14391156831212787f);  // 10000^(-i/64)
    float ang = (float)tt * freq;
    float s, c;
    sincosf(ang, &s, &c);
    cos_t[idx] = c;
    sin_t[idx] = s;
    return;
  }

  const int c0 = bx * 64, r0 = by * 64;
  const int cq = t & 15, rr = t >> 4;
#pragma unroll
  for (int i = 0; i < 4; ++i) {
    int r = rr + i * 16;
    float4 v = *(const float4*)&in[(size_t)(r0 + r) * C + c0 + cq * 4];
    tile[r][cq * 4 + 0] = f2bf(v.x);
    tile[r][cq * 4 + 1] = f2bf(v.y);
    tile[r][cq * 4 + 2] = f2bf(v.z);
    tile[r][cq * 4 + 3] = f2bf(v.w);
  }
  __syncthreads();
#pragma unroll
  for (int ii = 0; ii < 4; ++ii) {
    int c = rr + ii * 16;
    int n = c0 + c;
    int np = n;
    if (permute && n < 4096) {
      int d = n & 127, blk = d >> 5;
      int dd = (blk == 1) ? d + 32 : (blk == 2) ? d - 32 : d;
      np = (n & ~127) | dd;
    }
    us4 o;
#pragma unroll
    for (int jj = 0; jj < 4; ++jj) o[jj] = tile[cq * 4 + jj][c];
    *(us4*)&out[(size_t)np * R + r0 + cq * 4] = o;
  }
}

// ---------------------------------------------------------------------------
// 256x256 8-wave GEMM engine, 4-phase LDS-minimal schedule.
// Measured-best config (rounds 6/14: 202-206us) restored, with the wait
// soundness now PROVEN in the correct unit (vmcnt counts per-thread load
// ENTRIES; each STAGE_*_HALF = 2 entries):
//  - tile entry: outstanding 8 = {A0,A0,B0,B0,B1,B1,A1,A1}; WAITV(2)
//    confirms oldest 6 = A0,B0,B1 = exactly ph1's LDB2+LDA(0) read set.
//  - mid: outstanding 6 = {A1,A1,nA0,nA0,nB0,nB0}; WAITV(4) confirms
//    exactly A1 = ph3's LDA(1) read set.
// Both sound AND minimal (r15's WAITV(2) mid / r16's WAITV(1) entry were
// over-strong -> stalled on loads issued only 1-2 phases earlier).
// setprio(1) around MFMA clusters: removing it cost ~24us (r15 A/B).
// ---------------------------------------------------------------------------

#define BARR __builtin_amdgcn_s_barrier()
#define WAITV(N) asm volatile("s_waitcnt vmcnt(" #N ")" ::: "memory")

#define STAGE_A_HALF(BUF, T, H)                                                \
  do {                                                                         \
    const int k0_ = (T) * 64;                                                  \
    _Pragma("unroll") for (int i_ = 0; i_ < 2; ++i_) {                         \
      int c_ = i_ * 512 + tid;                                                 \
      int rp_ = c_ >> 3, s_ = c_ & 7;                                          \
      int row_ = (rp_ & 63) + (H) * 64 + (rp_ >> 6) * 128;                     \
      gl_lds16(Ag + (size_t)row_ * 2048 + k0_ + ((s_ ^ (row_ & 7)) << 3),      \
               &As[BUF][row_ * 64 + s_ * 8]);                                  \
    }                                                                          \
  } while (0)

#define STAGE_B_HALF(BUF, T, H)                                                \
  do {                                                                         \
    const int k0_ = (T) * 64;                                                  \
    _Pragma("unroll") for (int i_ = 0; i_ < 2; ++i_) {                         \
      int c_ = i_ * 512 + tid;                                                 \
      int rp_ = c_ >> 3, s_ = c_ & 7;                                          \
      int row_ = (rp_ & 31) + (H) * 32 + (rp_ >> 5) * 64;                      \
      gl_lds16(Bg + (size_t)row_ * 2048 + k0_ + ((s_ ^ (row_ & 7)) << 3),      \
               &Bs[BUF][row_ * 64 + s_ * 8]);                                  \
    }                                                                          \
  } while (0)

#define LDA(mh)                                                                \
  _Pragma("unroll") for (int m2_ = 0; m2_ < 4; ++m2_)                          \
  _Pragma("unroll") for (int kk_ = 0; kk_ < 2; ++kk_) {                        \
    int R_ = wm * 128 + (mh) * 64 + m2_ * 16 + ln;                             \
    av[m2_][kk_] = *(const bf16x8*)&Ab[R_ * 64 +                               \
        (((kk_ * 64 + g * 16) ^ ((R_ & 7) << 4)) >> 1)];                       \
  }

#define LDB2                                                                   \
  _Pragma("unroll") for (int nh_ = 0; nh_ < 2; ++nh_)                          \
  _Pragma("unroll") for (int n2_ = 0; n2_ < 2; ++n2_)                          \
  _Pragma("unroll") for (int kk_ = 0; kk_ < 2; ++kk_) {                        \
    int R_ = wn * 64 + nh_ * 32 + n2_ * 16 + ln;                               \
    bv[nh_ * 2 + n2_][kk_] = *(const bf16x8*)&Bb[R_ * 64 +                     \
        (((kk_ * 64 + g * 16) ^ ((R_ & 7) << 4)) >> 1)];                       \
  }

#define MF16(mh, nh)                                                           \
  do {                                                                         \
    __builtin_amdgcn_s_setprio(1);                                             \
    _Pragma("unroll") for (int m2_ = 0; m2_ < 4; ++m2_)                        \
    _Pragma("unroll") for (int n2_ = 0; n2_ < 2; ++n2_)                        \
    _Pragma("unroll") for (int kk_ = 0; kk_ < 2; ++kk_)                        \
      acc[(mh) * 4 + m2_][(nh) * 2 + n2_] = mfma_bf16(                         \
          av[m2_][kk_], bv[(nh) * 2 + n2_][kk_],                               \
          acc[(mh) * 4 + m2_][(nh) * 2 + n2_]);                                \
    __builtin_amdgcn_s_setprio(0);                                             \
  } while (0)

#define GEMM_ENGINE_4PH(NT)                                                    \
  STAGE_A_HALF(0, 0, 0); STAGE_B_HALF(0, 0, 0);                                \
  STAGE_B_HALF(0, 0, 1); STAGE_A_HALF(0, 0, 1);                                \
  for (int t = 0; t < (NT); ++t) {                                             \
    const int p_ = t & 1, q_ = p_ ^ 1;                                         \
    const unsigned short* Ab = &As[p_][0];                                     \
    const unsigned short* Bb = &Bs[p_][0];                                     \
    const bool pf_ = (t + 1 < (NT));                                           \
    WAITV(2);   /* entries: confirm oldest 6 = cur.{A0,B0,B1} */               \
    BARR;                                                                      \
    /* ph1: all B + A-half0 reads; stage next.A0 */                            \
    LDB2; LDA(0);                                                              \
    if (pf_) STAGE_A_HALF(q_, t + 1, 0);                                       \
    MF16(0, 0);                                                                \
    /* ph2: stage next.B0 */                                                   \
    if (pf_) STAGE_B_HALF(q_, t + 1, 0);                                       \
    MF16(0, 1);                                                                \
    if (pf_) { WAITV(4); } else { WAITV(0); }  /* confirm cur.A1 exactly */    \
    BARR;                                                                      \
    /* ph3: A-half1 reads; stage next.B1 */                                    \
    LDA(1);                                                                    \
    if (pf_) STAGE_B_HALF(q_, t + 1, 1);                                       \
    MF16(1, 0);                                                                \
    /* ph4: stage next.A1 */                                                   \
    if (pf_) STAGE_A_HALF(q_, t + 1, 1);                                       \
    MF16(1, 1);                                                                \
  }

// ---------------------------------------------------------------------------
// GEMM1: qkv = x @ W_attn + b_attn, fused RoPE epilogue (permuted q/k cols).
// q pre-scaled by (1/sqrt(D))*log2(e) (exp2-domain softmax). v-epilogue
// emits vt bf16 [z][D][T] via LDS transpose (coalesced 256B-segment writes).
// Grid 768; XCD x owns mtiles [4x,4x+4) x all 24 ntiles, n-fastest.
// ---------------------------------------------------------------------------
__global__ __launch_bounds__(512, 2) void gemm_qkv_kernel(
    const unsigned short* __restrict__ xbf, const unsigned short* __restrict__ wt,
    const float* __restrict__ bias, const float* __restrict__ cost,
    const float* __restrict__ sint, float* __restrict__ out_k,
    float* __restrict__ out_v, unsigned short* __restrict__ qbf,
    unsigned short* __restrict__ kbf, unsigned short* __restrict__ vtb) {
  __shared__ __attribute__((aligned(16))) unsigned short As[2][256 * 64];
  __shared__ __attribute__((aligned(16))) unsigned short Bs[2][256 * 64];
  const int tid = threadIdx.x;
  const int wid = tid >> 6, l = tid & 63, g = l >> 4, ln = l & 15;
  const int wm = wid >> 2, wn = wid & 3;
  const int xcd = blockIdx.x & 7, local = blockIdx.x >> 3;  // local in [0,96)
  const int mtile = xcd * 4 + (local & 3);
  const int ntile = local >> 2;
  const unsigned short* Ag = xbf + (size_t)(mtile * 256) * 2048;
  const unsigned short* Bg = wt + (size_t)(ntile * 256) * 2048;

  f32x4 acc[8][4];
#pragma unroll
  for (int i = 0; i < 8; ++i)
#pragma unroll
    for (int j = 0; j < 4; ++j) acc[i][j] = (f32x4){0.f, 0.f, 0.f, 0.f};
  bf16x8 av[4][2], bv[4][2];

  GEMM_ENGINE_4PH(32);

  // ---- epilogue ----
  const int colb = ntile * 256 + wn * 64;   // permuted col base of this wave
  const int p = colb >> 11;                 // block-uniform (ntile-determined)
  const int h = (colb >> 7) & 15;
  const int Mb = mtile * 256 + wm * 128;

  if (p == 2) {  // v: f32 out + bf16 V^T via LDS transpose
    __syncthreads();   // all waves done with main-loop LDS
    unsigned short* reg = (wid < 4) ? &As[0][0] + wid * 8192
                                    : &Bs[0][0] + (wid - 4) * 8192;  // 16KB/wave
    float bvv[4];
#pragma unroll
    for (int nf = 0; nf < 4; ++nf) bvv[nf] = bias[colb + nf * 16 + ln];
    const int dbase = (wn & 1) * 64;
#pragma unroll
    for (int mf = 0; mf < 8; ++mf) {
      int t0 = Mb + mf * 16 + g * 4;
      int bb = t0 >> 11, tt = t0 & 2047;
      size_t base = ((size_t)(bb * 16 + h) * 2048 + tt) * 128;
#pragma unroll
      for (int nf = 0; nf < 4; ++nf) {
        int dl = nf * 16 + ln;                 // wave-local dim 0..63
        us4 pack;
#pragma unroll
        for (int r = 0; r < 4; ++r) {
          float val = acc[mf][nf][r] + bvv[nf];
          out_v[base + (size_t)r * 128 + dbase + dl] = val;
          pack[r] = f2bf(val);
        }
        int byt = (mf * 32 + g * 8) ^ ((dl & 7) << 4);   // swizzled 8B slot
        *(us4*)&reg[dl * 128 + (byt >> 1)] = pack;       // LDS[dl][t] transposed
      }
    }
    asm volatile("s_waitcnt lgkmcnt(0)" ::: "memory");   // wave-private region
    __builtin_amdgcn_sched_barrier(0);
    const size_t vtz = (size_t)((Mb >> 11) * 16 + h) * (128 * 2048);
    const int tbase = (Mb & 2047);           // wave's 128 tokens (wm in Mb)
#pragma unroll
    for (int it = 0; it < 16; ++it) {
      int dl = it * 4 + (l >> 4);
      int byt = ((l & 15) * 16) ^ ((dl & 7) << 4);
      us8 v8 = *(const us8*)&reg[dl * 128 + (byt >> 1)];
      *(us8*)&vtb[vtz + (size_t)(dbase + dl) * 2048 + tbase + (l & 15) * 8] = v8;
    }
  } else {  // q (p==0) or k (p==1): RoPE; partners are acc[.][nf] / acc[.][nf+2]
    // q additionally scaled by 1/sqrt(128) * log2(e) for exp2-domain softmax
    const float sc2 = 0.12751743681128098f;
    const int half32 = (wn & 1) * 32;
    float blo[2], bhi[2];
#pragma unroll
    for (int nf = 0; nf < 2; ++nf) {
      int d_lo = half32 + nf * 16 + ln;
      blo[nf] = bias[p * 2048 + h * 128 + d_lo];
      bhi[nf] = bias[p * 2048 + h * 128 + d_lo + 64];
    }
#pragma unroll
    for (int mf = 0; mf < 8; ++mf)
#pragma unroll
      for (int r = 0; r < 4; ++r) {
        int m = Mb + mf * 16 + g * 4 + r;
        int b = m >> 11, t = m & 2047;
        size_t base = ((size_t)(b * 16 + h) * 2048 + t) * 128;
#pragma unroll
        for (int nf = 0; nf < 2; ++nf) {
          int d_lo = half32 + nf * 16 + ln;
          float cv = cost[t * 64 + d_lo], sv = sint[t * 64 + d_lo];
          float a = acc[mf][nf][r] + blo[nf];
          float bq = acc[mf][nf + 2][r] + bhi[nf];
          float lo = a * cv - bq * sv;
          float hi = bq * cv + a * sv;
          if (p == 0) {
            qbf[base + d_lo] = f2bf(lo * sc2);
            qbf[base + d_lo + 64] = f2bf(hi * sc2);
          } else {
            out_k[base + d_lo] = lo;
            out_k[base + d_lo + 64] = hi;
            kbf[base + d_lo] = f2bf(lo);
            kbf[base + d_lo + 64] = f2bf(hi);
          }
        }
      }
  }
}

// ---------------------------------------------------------------------------
// GEMM2: out = y @ W_proj + b_proj (f32). Grid 256; XCD x owns mtiles
// [4x,4x+4) x all 8 ntiles, n-fastest.
// ---------------------------------------------------------------------------
__global__ __launch_bounds__(512, 2) void gemm_proj_kernel(
    const unsigned short* __restrict__ ybf, const unsigned short* __restrict__ wpt,
    const float* __restrict__ bias, float* __restrict__ out) {
  __shared__ __attribute__((aligned(16))) unsigned short As[2][256 * 64];
  __shared__ __attribute__((aligned(16))) unsigned short Bs[2][256 * 64];
  const int tid = threadIdx.x;
  const int wid = tid >> 6, l = tid & 63, g = l >> 4, ln = l & 15;
  const int wm = wid >> 2, wn = wid & 3;
  const int xcd = blockIdx.x & 7, local = blockIdx.x >> 3;  // local in [0,32)
  const int mtile = xcd * 4 + (local & 3);
  const int ntile = local >> 2;
  const unsigned short* Ag = ybf + (size_t)(mtile * 256) * 2048;
  const unsigned short* Bg = wpt + (size_t)(ntile * 256) * 2048;

  f32x4 acc[8][4];
#pragma unroll
  for (int i = 0; i < 8; ++i)
#pragma unroll
    for (int j = 0; j < 4; ++j) acc[i][j] = (f32x4){0.f, 0.f, 0.f, 0.f};
  bf16x8 av[4][2], bv[4][2];

  GEMM_ENGINE_4PH(32);

  const int n0 = ntile * 256 + wn * 64;
  const int Mb = mtile * 256 + wm * 128;
  float bvv[4];
#pragma unroll
  for (int nf = 0; nf < 4; ++nf) bvv[nf] = bias[n0 + nf * 16 + ln];
#pragma unroll
  for (int mf = 0; mf < 8; ++mf)
#pragma unroll
    for (int r = 0; r < 4; ++r) {
      int m = Mb + mf * 16 + g * 4 + r;
      size_t rb = (size_t)m * 2048 + n0;
#pragma unroll
      for (int nf = 0; nf < 4; ++nf)
        out[rb + nf * 16 + ln] = acc[mf][nf][r] + bvv[nf];
    }
}

// ---------------------------------------------------------------------------
// Flash attention (round-13 structure unchanged: exp2-domain softmax, lazy
// max-reduce, deferred sum-reduce, no setprio). Grid 1024 = z x qp.
// ---------------------------------------------------------------------------
__global__ __launch_bounds__(256, 2) void attn_kernel(
    const unsigned short* __restrict__ qbf, const unsigned short* __restrict__ kbf,
    const unsigned short* __restrict__ vtbf, unsigned short* __restrict__ ybf) {
  __shared__ __attribute__((aligned(16))) unsigned short Ks[2][64 * 128];
  __shared__ __attribute__((aligned(16))) unsigned short Vs[2][128 * 64];
  __shared__ __attribute__((aligned(16))) __bf16 Ps[4][32 * 64];
  const int tid = threadIdx.x;
  const int w = tid >> 6, l = tid & 63, g = l >> 4, ln = l & 15;
  const int bid = blockIdx.x;
  const int z = (bid & 7) * 8 + ((bid >> 3) & 7);
  const int qp = 15 - (bid >> 6);
  const size_t zo = (size_t)z * (2048 * 128);
  const size_t zv = (size_t)z * (128 * 2048);
  const int Q0w = qp * 128 + w * 32;
  const int jn = 2 * qp + 2;
  const int jlw = 2 * qp + (w >> 1);
  __bf16* Pw = Ps[w];

  bf16x8 qv[2][4];
#pragma unroll
  for (int mf = 0; mf < 2; ++mf)
#pragma unroll
    for (int kk = 0; kk < 4; ++kk)
      qv[mf][kk] = *(const bf16x8*)
          &qbf[zo + (size_t)(Q0w + mf * 16 + ln) * 128 + kk * 32 + g * 8];

  f32x4 o[2][8];
#pragma unroll
  for (int mf = 0; mf < 2; ++mf)
#pragma unroll
    for (int nf = 0; nf < 8; ++nf) o[mf][nf] = (f32x4){0.f, 0.f, 0.f, 0.f};
  float mrun[2][4], lpart[2][4];
#pragma unroll
  for (int mf = 0; mf < 2; ++mf)
#pragma unroll
    for (int r = 0; r < 4; ++r) { mrun[mf][r] = -3e38f; lpart[mf][r] = 0.f; }

#define STAGE_KV(J, B)                                                         \
  do {                                                                         \
    const int kv0_ = (J) << 6;                                                 \
    _Pragma("unroll") for (int i_ = 0; i_ < 4; ++i_) {                         \
      int c_ = i_ * 256 + tid;                                                 \
      int r_ = c_ >> 4, s_ = c_ & 15;                                          \
      gl_lds16(kbf + zo + (size_t)(kv0_ + r_) * 128 +                          \
                   (((s_ * 16) ^ ((r_ & 7) << 4)) >> 1),                       \
               &Ks[B][c_ * 8]);                                                \
    }                                                                          \
    _Pragma("unroll") for (int i_ = 0; i_ < 4; ++i_) {                         \
      int c_ = i_ * 256 + tid;                                                 \
      int d_ = c_ >> 3, s_ = c_ & 7;                                           \
      gl_lds16(vtbf + zv + (size_t)d_ * 2048 + kv0_ +                          \
                   (((s_ * 16) ^ ((d_ & 7) << 4)) >> 1),                       \
               &Vs[B][c_ * 8]);                                                \
    }                                                                          \
  } while (0)

  STAGE_KV(0, 0);
  STAGE_KV(1, 1);

  for (int j = 0; j < jn; ++j) {
    if (j + 1 < jn)
      asm volatile("s_waitcnt vmcnt(8)" ::: "memory");
    else
      asm volatile("s_waitcnt vmcnt(0)" ::: "memory");
    __builtin_amdgcn_s_barrier();
    const int bfr = j & 1;
    const unsigned short* Kb = Ks[bfr];
    const unsigned short* Vb = Vs[bfr];

    if (j <= jlw) {
      const int kv0 = j << 6;
      f32x4 s[2][4];
#pragma unroll
      for (int mf = 0; mf < 2; ++mf)
#pragma unroll
        for (int nf = 0; nf < 4; ++nf) s[mf][nf] = (f32x4){0.f, 0.f, 0.f, 0.f};
#pragma unroll
      for (int kk = 0; kk < 4; ++kk) {
        bf16x8 kf[4];
#pragma unroll
        for (int nf = 0; nf < 4; ++nf) {
          int rr = nf * 16 + ln;
          kf[nf] = *(const bf16x8*)
              &Kb[rr * 128 + (((kk * 64 + g * 16) ^ ((rr & 7) << 4)) >> 1)];
        }
#pragma unroll
        for (int mf = 0; mf < 2; ++mf)
#pragma unroll
          for (int nf = 0; nf < 4; ++nf)
            s[mf][nf] = mfma_bf16(qv[mf][kk], kf[nf], s[mf][nf]);
      }

      if (j == jlw) {
#pragma unroll
        for (int mf = 0; mf < 2; ++mf)
#pragma unroll
          for (int nf = 0; nf < 4; ++nf)
#pragma unroll
            for (int r = 0; r < 4; ++r)
              if (kv0 + nf * 16 + ln > Q0w + mf * 16 + g * 4 + r)
                s[mf][nf][r] = -3e38f;
      }

      // in-lane (partial) row max over this lane's 4 cols
      float mxl[2][4];
#pragma unroll
      for (int mf = 0; mf < 2; ++mf)
#pragma unroll
        for (int r = 0; r < 4; ++r)
          mxl[mf][r] = fmaxf(fmaxf(s[mf][0][r], s[mf][1][r]),
                             fmaxf(s[mf][2][r], s[mf][3][r]));

      // lazy defer-max (T13): __any over partial maxes is an equivalent trigger
      float dm = 0.f;
#pragma unroll
      for (int mf = 0; mf < 2; ++mf)
#pragma unroll
        for (int r = 0; r < 4; ++r) dm = fmaxf(dm, mxl[mf][r] - mrun[mf][r]);
      if (__any(dm > 11.5416f)) {   // exp2(11.5416) == e^8
#pragma unroll
        for (int mf = 0; mf < 2; ++mf)
#pragma unroll
          for (int r = 0; r < 4; ++r) {
            float m0 = mxl[mf][r];
            m0 = fmaxf(m0, __shfl_xor(m0, 1));
            m0 = fmaxf(m0, __shfl_xor(m0, 2));
            m0 = fmaxf(m0, __shfl_xor(m0, 4));
            m0 = fmaxf(m0, __shfl_xor(m0, 8));
            float mn = fmaxf(mrun[mf][r], m0);
            float al = exp2f(mrun[mf][r] - mn);
            mrun[mf][r] = mn;
            lpart[mf][r] *= al;
#pragma unroll
            for (int nf = 0; nf < 8; ++nf) o[mf][nf][r] *= al;
          }
      }

      // P = exp2(S - m), per-lane partial sums (reduced once at the end)
#pragma unroll
      for (int mf = 0; mf < 2; ++mf)
#pragma unroll
        for (int r = 0; r < 4; ++r) {
          const float m0 = mrun[mf][r];
          const int row_l = mf * 16 + g * 4 + r;
          float rs = 0.f;
#pragma unroll
          for (int nf = 0; nf < 4; ++nf) {
            float pv = exp2f(s[mf][nf][r] - m0);
            rs += pv;
            int byte = ((nf * 16 + ln) << 1) ^ ((row_l & 7) << 4);
            Pw[row_l * 64 + (byte >> 1)] = (__bf16)pv;
          }
          lpart[mf][r] += rs;
        }

      asm volatile("s_waitcnt lgkmcnt(0)" ::: "memory");
      __builtin_amdgcn_sched_barrier(0);

#pragma unroll
      for (int kk2 = 0; kk2 < 2; ++kk2) {
        bf16x8 pa[2];
#pragma unroll
        for (int mf = 0; mf < 2; ++mf) {
          int pr = mf * 16 + ln;
          int byte = (kk2 * 64 + g * 16) ^ ((pr & 7) << 4);
          pa[mf] = *(const bf16x8*)&Pw[pr * 64 + (byte >> 1)];
        }
#pragma unroll
        for (int nf2 = 0; nf2 < 8; ++nf2) {
          int dr = nf2 * 16 + ln;
          bf16x8 vf = *(const bf16x8*)
              &Vb[dr * 64 + (((kk2 * 64 + g * 16) ^ ((dr & 7) << 4)) >> 1)];
#pragma unroll
          for (int mf = 0; mf < 2; ++mf)
            o[mf][nf2] = mfma_bf16(pa[mf], vf, o[mf][nf2]);
        }
      }
    }

    __builtin_amdgcn_s_barrier();
    __builtin_amdgcn_sched_barrier(0);
    if (j + 2 < jn) STAGE_KV(j + 2, bfr);
  }
#undef STAGE_KV

  // final: one 16-lane sum reduce per row, then normalize + write y
  const int b = z >> 4, h = z & 15;
#pragma unroll
  for (int mf = 0; mf < 2; ++mf)
#pragma unroll
    for (int r = 0; r < 4; ++r) {
      float rs = lpart[mf][r];
      rs += __shfl_xor(rs, 1);
      rs += __shfl_xor(rs, 2);
      rs += __shfl_xor(rs, 4);
      rs += __shfl_xor(rs, 8);
      float inv = 1.f / rs;
      int t = Q0w + mf * 16 + g * 4 + r;
      size_t rb = ((size_t)b * 2048 + t) * 2048 + h * 128;
#pragma unroll
      for (int nf2 = 0; nf2 < 8; ++nf2)
        ybf[rb + nf2 * 16 + ln] = f2bf(o[mf][nf2][r] * inv);
    }
}

// ---------------------------------------------------------------------------
// Launch
// ---------------------------------------------------------------------------
extern "C" void kernel_launch(void* const* d_in, const int* in_sizes, int n_in,
                              void* d_out, int out_size, void* d_ws, size_t ws_size,
                              hipStream_t stream) {
  (void)in_sizes; (void)n_in; (void)out_size; (void)ws_size;
  const float* x      = (const float*)d_in[0];
  const float* W_attn = (const float*)d_in[1];
  const float* b_attn = (const float*)d_in[2];
  const float* W_proj = (const float*)d_in[3];
  const float* b_proj = (const float*)d_in[4];

  float* out   = (float*)d_out;                 // [8192][2048]
  float* out_k = out + 16777216;                // [64][2048][128]
  float* out_v = out + 33554432;                // [64][2048][128]

  char* ws = (char*)d_ws;
  unsigned short* q_bf  = (unsigned short*)(ws + 0);           // 33.5 MB
  unsigned short* k_bf  = (unsigned short*)(ws + 33554432);    // 33.5 MB
  unsigned short* vt_bf = (unsigned short*)(ws + 67108864);    // 33.5 MB
  unsigned short* x_bf  = (unsigned short*)(ws + 100663296);   // 33.5 MB (reused as y2d)
  unsigned short* y2d   = x_bf;                                // x_bf dead after GEMM1
  unsigned short* wt    = (unsigned short*)(ws + 134217728);   // 25.2 MB
  unsigned short* wpt   = (unsigned short*)(ws + 159383552);   // 8.4 MB
  float* cos_t = (float*)(ws + 167772160);                     // 0.5 MB
  float* sin_t = (float*)(ws + 168296448);                     // 0.5 MB

  prep_kernel<<<6656, 256, 0, stream>>>(x, x_bf, W_attn, wt, W_proj, wpt,
                                        cos_t, sin_t);
  gemm_qkv_kernel<<<768, 512, 0, stream>>>(x_bf, wt, b_attn, cos_t, sin_t,
                                           out_k, out_v, q_bf, k_bf, vt_bf);
  attn_kernel<<<1024, 256, 0, stream>>>(q_bf, k_bf, vt_bf, y2d);
  gemm_proj_kernel<<<256, 512, 0, stream>>>(y2d, wpt, b_proj, out);
}

// Round 18
// 406.772 us; speedup vs baseline: 1.0813x; 1.0117x over previous
//
#include <hip/hip_runtime.h>

// ---------------------------------------------------------------------------
// CausalSelfAttention on MI355X (gfx950), bf16 MFMA pipeline.
// Shapes: B=4, T=2048, C=2048, H=16, D=128. N_qkv=6144.
// d_out = [ out f32 (B,T,C) | k f32 (B,H,T,D) | v f32 (B,H,T,D) ]
// ---------------------------------------------------------------------------

typedef __attribute__((ext_vector_type(4))) float f32x4;
typedef __attribute__((ext_vector_type(8))) __bf16 bf16x8;
typedef __attribute__((ext_vector_type(4))) unsigned short us4;
typedef __attribute__((ext_vector_type(8))) unsigned short us8;

__device__ __forceinline__ unsigned short f2bf(float f) {
  unsigned u = __float_as_uint(f);
  u += 0x7FFFu + ((u >> 16) & 1u);   // round-to-nearest-even
  return (unsigned short)(u >> 16);
}

__device__ __forceinline__ void gl_lds16(const void* g, void* l) {
  __builtin_amdgcn_global_load_lds(
      (const __attribute__((address_space(1))) void*)g,
      (__attribute__((address_space(3))) void*)l, 16, 0, 0);
}

__device__ __forceinline__ f32x4 mfma_bf16(bf16x8 a, bf16x8 b, f32x4 c) {
  return __builtin_amdgcn_mfma_f32_16x16x32_bf16(a, b, c, 0, 0, 0);
}

// ---------------------------------------------------------------------------
// Fused prep kernel (W_proj transpose moved into the attn launch -- it is
// consumed only by gemm_proj, so it overlaps with attention instead of
// serializing here):
//   [0,2048)        conv_bf16 of x             (grid-stride, 8 float4/thread)
//   [2048,5120)     transpose W_attn (permuted) 96 x 32 tiles
//   [5120,5632)     rope cos/sin table
// ---------------------------------------------------------------------------
__global__ __launch_bounds__(256) void prep_kernel(
    const float* __restrict__ x, unsigned short* __restrict__ x_bf,
    const float* __restrict__ W_attn, unsigned short* __restrict__ wt,
    float* __restrict__ cos_t, float* __restrict__ sin_t) {
  __shared__ unsigned short tile[64][68];
  const int bid = blockIdx.x;
  const int t = threadIdx.x;

  if (bid < 2048) {  // ---- conv_bf16 ----
    int idx = bid * 256 + t;
    for (; idx < 4194304; idx += 2048 * 256) {
      float4 v = ((const float4*)x)[idx];
      us4 o;
      o[0] = f2bf(v.x); o[1] = f2bf(v.y); o[2] = f2bf(v.z); o[3] = f2bf(v.w);
      ((us4*)x_bf)[idx] = o;
    }
    return;
  }
  if (bid >= 5120) {  // ---- rope table ----
    int idx = (bid - 5120) * 256 + t;
    int tt = idx >> 6, i = idx & 63;
    float freq = __expf(-(float)i * 0.14391156831212787f);  // 10000^(-i/64)
    float ang = (float)tt * freq;
    float s, c;
    sincosf(ang, &s, &c);
    cos_t[idx] = c;
    sin_t[idx] = s;
    return;
  }

  // ---- transpose W_attn (permuted) ----
  const int loc = bid - 2048;
  const int bx = loc % 96, by = loc / 96;
  const int c0 = bx * 64, r0 = by * 64;
  const int cq = t & 15, rr = t >> 4;
#pragma unroll
  for (int i = 0; i < 4; ++i) {
    int r = rr + i * 16;
    float4 v = *(const float4*)&W_attn[(size_t)(r0 + r) * 6144 + c0 + cq * 4];
    tile[r][cq * 4 + 0] = f2bf(v.x);
    tile[r][cq * 4 + 1] = f2bf(v.y);
    tile[r][cq * 4 + 2] = f2bf(v.z);
    tile[r][cq * 4 + 3] = f2bf(v.w);
  }
  __syncthreads();
#pragma unroll
  for (int ii = 0; ii < 4; ++ii) {
    int c = rr + ii * 16;
    int n = c0 + c;
    int np = n;
    if (n < 4096) {  // q/k sections: swap middle 32-blocks (RoPE pairing)
      int d = n & 127, blk = d >> 5;
      int dd = (blk == 1) ? d + 32 : (blk == 2) ? d - 32 : d;
      np = (n & ~127) | dd;
    }
    us4 o;
#pragma unroll
    for (int jj = 0; jj < 4; ++jj) o[jj] = tile[cq * 4 + jj][c];
    *(us4*)&wt[(size_t)np * 2048 + r0 + cq * 4] = o;
  }
}

// ---------------------------------------------------------------------------
// 256x256 8-wave GEMM engine, 4-phase LDS-minimal schedule.
// Measured-best config (rounds 6/14/17: 202-206us). Wait soundness in the
// correct unit (vmcnt counts per-thread load ENTRIES; each STAGE = 2):
//  - entry: outstanding 8 = {A0,A0,B0,B0,B1,B1,A1,A1}; WAITV(2) confirms
//    oldest 6 = A0,B0,B1 = exactly ph1's LDB2+LDA(0) read set.
//  - mid: outstanding 6 = {A1,A1,nA0,nA0,nB0,nB0}; WAITV(4) confirms A1.
// setprio(1) around MFMA clusters (removing it cost ~24us, r15 A/B).
// ---------------------------------------------------------------------------

#define BARR __builtin_amdgcn_s_barrier()
#define WAITV(N) asm volatile("s_waitcnt vmcnt(" #N ")" ::: "memory")

#define STAGE_A_HALF(BUF, T, H)                                                \
  do {                                                                         \
    const int k0_ = (T) * 64;                                                  \
    _Pragma("unroll") for (int i_ = 0; i_ < 2; ++i_) {                         \
      int c_ = i_ * 512 + tid;                                                 \
      int rp_ = c_ >> 3, s_ = c_ & 7;                                          \
      int row_ = (rp_ & 63) + (H) * 64 + (rp_ >> 6) * 128;                     \
      gl_lds16(Ag + (size_t)row_ * 2048 + k0_ + ((s_ ^ (row_ & 7)) << 3),      \
               &As[BUF][row_ * 64 + s_ * 8]);                                  \
    }                                                                          \
  } while (0)

#define STAGE_B_HALF(BUF, T, H)                                                \
  do {                                                                         \
    const int k0_ = (T) * 64;                                                  \
    _Pragma("unroll") for (int i_ = 0; i_ < 2; ++i_) {                         \
      int c_ = i_ * 512 + tid;                                                 \
      int rp_ = c_ >> 3, s_ = c_ & 7;                                          \
      int row_ = (rp_ & 31) + (H) * 32 + (rp_ >> 5) * 64;                      \
      gl_lds16(Bg + (size_t)row_ * 2048 + k0_ + ((s_ ^ (row_ & 7)) << 3),      \
               &Bs[BUF][row_ * 64 + s_ * 8]);                                  \
    }                                                                          \
  } while (0)

#define LDA(mh)                                                                \
  _Pragma("unroll") for (int m2_ = 0; m2_ < 4; ++m2_)                          \
  _Pragma("unroll") for (int kk_ = 0; kk_ < 2; ++kk_) {                        \
    int R_ = wm * 128 + (mh) * 64 + m2_ * 16 + ln;                             \
    av[m2_][kk_] = *(const bf16x8*)&Ab[R_ * 64 +                               \
        (((kk_ * 64 + g * 16) ^ ((R_ & 7) << 4)) >> 1)];                       \
  }

#define LDB2                                                                   \
  _Pragma("unroll") for (int nh_ = 0; nh_ < 2; ++nh_)                          \
  _Pragma("unroll") for (int n2_ = 0; n2_ < 2; ++n2_)                          \
  _Pragma("unroll") for (int kk_ = 0; kk_ < 2; ++kk_) {                        \
    int R_ = wn * 64 + nh_ * 32 + n2_ * 16 + ln;                               \
    bv[nh_ * 2 + n2_][kk_] = *(const bf16x8*)&Bb[R_ * 64 +                     \
        (((kk_ * 64 + g * 16) ^ ((R_ & 7) << 4)) >> 1)];                       \
  }

#define MF16(mh, nh)                                                           \
  do {                                                                         \
    __builtin_amdgcn_s_setprio(1);                                             \
    _Pragma("unroll") for (int m2_ = 0; m2_ < 4; ++m2_)                        \
    _Pragma("unroll") for (int n2_ = 0; n2_ < 2; ++n2_)                        \
    _Pragma("unroll") for (int kk_ = 0; kk_ < 2; ++kk_)                        \
      acc[(mh) * 4 + m2_][(nh) * 2 + n2_] = mfma_bf16(                         \
          av[m2_][kk_], bv[(nh) * 2 + n2_][kk_],                               \
          acc[(mh) * 4 + m2_][(nh) * 2 + n2_]);                                \
    __builtin_amdgcn_s_setprio(0);                                             \
  } while (0)

#define GEMM_ENGINE_4PH(NT)                                                    \
  STAGE_A_HALF(0, 0, 0); STAGE_B_HALF(0, 0, 0);                                \
  STAGE_B_HALF(0, 0, 1); STAGE_A_HALF(0, 0, 1);                                \
  for (int t = 0; t < (NT); ++t) {                                             \
    const int p_ = t & 1, q_ = p_ ^ 1;                                         \
    const unsigned short* Ab = &As[p_][0];                                     \
    const unsigned short* Bb = &Bs[p_][0];                                     \
    const bool pf_ = (t + 1 < (NT));                                           \
    WAITV(2);   /* entries: confirm oldest 6 = cur.{A0,B0,B1} */               \
    BARR;                                                                      \
    /* ph1: all B + A-half0 reads; stage next.A0 */                            \
    LDB2; LDA(0);                                                              \
    if (pf_) STAGE_A_HALF(q_, t + 1, 0);                                       \
    MF16(0, 0);                                                                \
    /* ph2: stage next.B0 */                                                   \
    if (pf_) STAGE_B_HALF(q_, t + 1, 0);                                       \
    MF16(0, 1);                                                                \
    if (pf_) { WAITV(4); } else { WAITV(0); }  /* confirm cur.A1 exactly */    \
    BARR;                                                                      \
    /* ph3: A-half1 reads; stage next.B1 */                                    \
    LDA(1);                                                                    \
    if (pf_) STAGE_B_HALF(q_, t + 1, 1);                                       \
    MF16(1, 0);                                                                \
    /* ph4: stage next.A1 */                                                   \
    if (pf_) STAGE_A_HALF(q_, t + 1, 1);                                       \
    MF16(1, 1);                                                                \
  }

// ---------------------------------------------------------------------------
// GEMM1: qkv = x @ W_attn + b_attn, fused RoPE epilogue (permuted q/k cols).
// q pre-scaled by (1/sqrt(D))*log2(e) (exp2-domain softmax). v-epilogue
// emits vt bf16 [z][D][T] via LDS transpose (coalesced 256B-segment writes).
// Grid 768; XCD x owns mtiles [4x,4x+4) x all 24 ntiles, n-fastest.
// ---------------------------------------------------------------------------
__global__ __launch_bounds__(512, 2) void gemm_qkv_kernel(
    const unsigned short* __restrict__ xbf, const unsigned short* __restrict__ wt,
    const float* __restrict__ bias, const float* __restrict__ cost,
    const float* __restrict__ sint, float* __restrict__ out_k,
    float* __restrict__ out_v, unsigned short* __restrict__ qbf,
    unsigned short* __restrict__ kbf, unsigned short* __restrict__ vtb) {
  __shared__ __attribute__((aligned(16))) unsigned short As[2][256 * 64];
  __shared__ __attribute__((aligned(16))) unsigned short Bs[2][256 * 64];
  const int tid = threadIdx.x;
  const int wid = tid >> 6, l = tid & 63, g = l >> 4, ln = l & 15;
  const int wm = wid >> 2, wn = wid & 3;
  const int xcd = blockIdx.x & 7, local = blockIdx.x >> 3;  // local in [0,96)
  const int mtile = xcd * 4 + (local & 3);
  const int ntile = local >> 2;
  const unsigned short* Ag = xbf + (size_t)(mtile * 256) * 2048;
  const unsigned short* Bg = wt + (size_t)(ntile * 256) * 2048;

  f32x4 acc[8][4];
#pragma unroll
  for (int i = 0; i < 8; ++i)
#pragma unroll
    for (int j = 0; j < 4; ++j) acc[i][j] = (f32x4){0.f, 0.f, 0.f, 0.f};
  bf16x8 av[4][2], bv[4][2];

  GEMM_ENGINE_4PH(32);

  // ---- epilogue ----
  const int colb = ntile * 256 + wn * 64;   // permuted col base of this wave
  const int p = colb >> 11;                 // block-uniform (ntile-determined)
  const int h = (colb >> 7) & 15;
  const int Mb = mtile * 256 + wm * 128;

  if (p == 2) {  // v: f32 out + bf16 V^T via LDS transpose
    __syncthreads();   // all waves done with main-loop LDS
    unsigned short* reg = (wid < 4) ? &As[0][0] + wid * 8192
                                    : &Bs[0][0] + (wid - 4) * 8192;  // 16KB/wave
    float bvv[4];
#pragma unroll
    for (int nf = 0; nf < 4; ++nf) bvv[nf] = bias[colb + nf * 16 + ln];
    const int dbase = (wn & 1) * 64;
#pragma unroll
    for (int mf = 0; mf < 8; ++mf) {
      int t0 = Mb + mf * 16 + g * 4;
      int bb = t0 >> 11, tt = t0 & 2047;
      size_t base = ((size_t)(bb * 16 + h) * 2048 + tt) * 128;
#pragma unroll
      for (int nf = 0; nf < 4; ++nf) {
        int dl = nf * 16 + ln;                 // wave-local dim 0..63
        us4 pack;
#pragma unroll
        for (int r = 0; r < 4; ++r) {
          float val = acc[mf][nf][r] + bvv[nf];
          out_v[base + (size_t)r * 128 + dbase + dl] = val;
          pack[r] = f2bf(val);
        }
        int byt = (mf * 32 + g * 8) ^ ((dl & 7) << 4);   // swizzled 8B slot
        *(us4*)&reg[dl * 128 + (byt >> 1)] = pack;       // LDS[dl][t] transposed
      }
    }
    asm volatile("s_waitcnt lgkmcnt(0)" ::: "memory");   // wave-private region
    __builtin_amdgcn_sched_barrier(0);
    const size_t vtz = (size_t)((Mb >> 11) * 16 + h) * (128 * 2048);
    const int tbase = (Mb & 2047);           // wave's 128 tokens (wm in Mb)
#pragma unroll
    for (int it = 0; it < 16; ++it) {
      int dl = it * 4 + (l >> 4);
      int byt = ((l & 15) * 16) ^ ((dl & 7) << 4);
      us8 v8 = *(const us8*)&reg[dl * 128 + (byt >> 1)];
      *(us8*)&vtb[vtz + (size_t)(dbase + dl) * 2048 + tbase + (l & 15) * 8] = v8;
    }
  } else {  // q (p==0) or k (p==1): RoPE; partners are acc[.][nf] / acc[.][nf+2]
    // q additionally scaled by 1/sqrt(128) * log2(e) for exp2-domain softmax
    const float sc2 = 0.12751743681128098f;
    const int half32 = (wn & 1) * 32;
    float blo[2], bhi[2];
#pragma unroll
    for (int nf = 0; nf < 2; ++nf) {
      int d_lo = half32 + nf * 16 + ln;
      blo[nf] = bias[p * 2048 + h * 128 + d_lo];
      bhi[nf] = bias[p * 2048 + h * 128 + d_lo + 64];
    }
#pragma unroll
    for (int mf = 0; mf < 8; ++mf)
#pragma unroll
      for (int r = 0; r < 4; ++r) {
        int m = Mb + mf * 16 + g * 4 + r;
        int b = m >> 11, t = m & 2047;
        size_t base = ((size_t)(b * 16 + h) * 2048 + t) * 128;
#pragma unroll
        for (int nf = 0; nf < 2; ++nf) {
          int d_lo = half32 + nf * 16 + ln;
          float cv = cost[t * 64 + d_lo], sv = sint[t * 64 + d_lo];
          float a = acc[mf][nf][r] + blo[nf];
          float bq = acc[mf][nf + 2][r] + bhi[nf];
          float lo = a * cv - bq * sv;
          float hi = bq * cv + a * sv;
          if (p == 0) {
            qbf[base + d_lo] = f2bf(lo * sc2);
            qbf[base + d_lo + 64] = f2bf(hi * sc2);
          } else {
            out_k[base + d_lo] = lo;
            out_k[base + d_lo + 64] = hi;
            kbf[base + d_lo] = f2bf(lo);
            kbf[base + d_lo + 64] = f2bf(hi);
          }
        }
      }
  }
}

// ---------------------------------------------------------------------------
// GEMM2: out = y @ W_proj + b_proj (f32). Grid 256; XCD x owns mtiles
// [4x,4x+4) x all 8 ntiles, n-fastest.
// ---------------------------------------------------------------------------
__global__ __launch_bounds__(512, 2) void gemm_proj_kernel(
    const unsigned short* __restrict__ ybf, const unsigned short* __restrict__ wpt,
    const float* __restrict__ bias, float* __restrict__ out) {
  __shared__ __attribute__((aligned(16))) unsigned short As[2][256 * 64];
  __shared__ __attribute__((aligned(16))) unsigned short Bs[2][256 * 64];
  const int tid = threadIdx.x;
  const int wid = tid >> 6, l = tid & 63, g = l >> 4, ln = l & 15;
  const int wm = wid >> 2, wn = wid & 3;
  const int xcd = blockIdx.x & 7, local = blockIdx.x >> 3;  // local in [0,32)
  const int mtile = xcd * 4 + (local & 3);
  const int ntile = local >> 2;
  const unsigned short* Ag = ybf + (size_t)(mtile * 256) * 2048;
  const unsigned short* Bg = wpt + (size_t)(ntile * 256) * 2048;

  f32x4 acc[8][4];
#pragma unroll
  for (int i = 0; i < 8; ++i)
#pragma unroll
    for (int j = 0; j < 4; ++j) acc[i][j] = (f32x4){0.f, 0.f, 0.f, 0.f};
  bf16x8 av[4][2], bv[4][2];

  GEMM_ENGINE_4PH(32);

  const int n0 = ntile * 256 + wn * 64;
  const int Mb = mtile * 256 + wm * 128;
  float bvv[4];
#pragma unroll
  for (int nf = 0; nf < 4; ++nf) bvv[nf] = bias[n0 + nf * 16 + ln];
#pragma unroll
  for (int mf = 0; mf < 8; ++mf)
#pragma unroll
    for (int r = 0; r < 4; ++r) {
      int m = Mb + mf * 16 + g * 4 + r;
      size_t rb = (size_t)m * 2048 + n0;
#pragma unroll
      for (int nf = 0; nf < 4; ++nf)
        out[rb + nf * 16 + ln] = acc[mf][nf][r] + bvv[nf];
    }
}

// ---------------------------------------------------------------------------
// Flash attention (round-13/17 structure unchanged) + fused W_proj transpose
// (blocks [1024,2048); consumed only by gemm_proj which launches after this
// kernel -- the transpose rides in attention's light tail instead of
// serializing in prep). Grid 2048.
// ---------------------------------------------------------------------------
__global__ __launch_bounds__(256, 2) void attn_kernel(
    const unsigned short* __restrict__ qbf, const unsigned short* __restrict__ kbf,
    const unsigned short* __restrict__ vtbf, unsigned short* __restrict__ ybf,
    const float* __restrict__ W_proj, unsigned short* __restrict__ wpt) {
  __shared__ __attribute__((aligned(16))) unsigned short Ks[2][64 * 128];
  __shared__ __attribute__((aligned(16))) unsigned short Vs[2][128 * 64];
  __shared__ __attribute__((aligned(16))) __bf16 Ps[4][32 * 64];
  const int tid = threadIdx.x;

  if (blockIdx.x >= 1024) {  // ---- W_proj transpose (reuses Ks[0] as tile) ----
    unsigned short (*tile)[68] = (unsigned short(*)[68])&Ks[0][0];
    const int loc = blockIdx.x - 1024;
    const int bx = loc & 31, by = loc >> 5;
    const int c0 = bx * 64, r0 = by * 64;
    const int cq = tid & 15, rr = tid >> 4;
#pragma unroll
    for (int i = 0; i < 4; ++i) {
      int r = rr + i * 16;
      float4 v = *(const float4*)&W_proj[(size_t)(r0 + r) * 2048 + c0 + cq * 4];
      tile[r][cq * 4 + 0] = f2bf(v.x);
      tile[r][cq * 4 + 1] = f2bf(v.y);
      tile[r][cq * 4 + 2] = f2bf(v.z);
      tile[r][cq * 4 + 3] = f2bf(v.w);
    }
    __syncthreads();
#pragma unroll
    for (int ii = 0; ii < 4; ++ii) {
      int c = rr + ii * 16;
      us4 o;
#pragma unroll
      for (int jj = 0; jj < 4; ++jj) o[jj] = tile[cq * 4 + jj][c];
      *(us4*)&wpt[(size_t)(c0 + c) * 2048 + r0 + cq * 4] = o;
    }
    return;
  }

  const int w = tid >> 6, l = tid & 63, g = l >> 4, ln = l & 15;
  const int bid = blockIdx.x;
  const int z = (bid & 7) * 8 + ((bid >> 3) & 7);
  const int qp = 15 - (bid >> 6);
  const size_t zo = (size_t)z * (2048 * 128);
  const size_t zv = (size_t)z * (128 * 2048);
  const int Q0w = qp * 128 + w * 32;
  const int jn = 2 * qp + 2;
  const int jlw = 2 * qp + (w >> 1);
  __bf16* Pw = Ps[w];

  bf16x8 qv[2][4];
#pragma unroll
  for (int mf = 0; mf < 2; ++mf)
#pragma unroll
    for (int kk = 0; kk < 4; ++kk)
      qv[mf][kk] = *(const bf16x8*)
          &qbf[zo + (size_t)(Q0w + mf * 16 + ln) * 128 + kk * 32 + g * 8];

  f32x4 o[2][8];
#pragma unroll
  for (int mf = 0; mf < 2; ++mf)
#pragma unroll
    for (int nf = 0; nf < 8; ++nf) o[mf][nf] = (f32x4){0.f, 0.f, 0.f, 0.f};
  float mrun[2][4], lpart[2][4];
#pragma unroll
  for (int mf = 0; mf < 2; ++mf)
#pragma unroll
    for (int r = 0; r < 4; ++r) { mrun[mf][r] = -3e38f; lpart[mf][r] = 0.f; }

#define STAGE_KV(J, B)                                                         \
  do {                                                                         \
    const int kv0_ = (J) << 6;                                                 \
    _Pragma("unroll") for (int i_ = 0; i_ < 4; ++i_) {                         \
      int c_ = i_ * 256 + tid;                                                 \
      int r_ = c_ >> 4, s_ = c_ & 15;                                          \
      gl_lds16(kbf + zo + (size_t)(kv0_ + r_) * 128 +                          \
                   (((s_ * 16) ^ ((r_ & 7) << 4)) >> 1),                       \
               &Ks[B][c_ * 8]);                                                \
    }                                                                          \
    _Pragma("unroll") for (int i_ = 0; i_ < 4; ++i_) {                         \
      int c_ = i_ * 256 + tid;                                                 \
      int d_ = c_ >> 3, s_ = c_ & 7;                                           \
      gl_lds16(vtbf + zv + (size_t)d_ * 2048 + kv0_ +                          \
                   (((s_ * 16) ^ ((d_ & 7) << 4)) >> 1),                       \
               &Vs[B][c_ * 8]);                                                \
    }                                                                          \
  } while (0)

  STAGE_KV(0, 0);
  STAGE_KV(1, 1);

  for (int j = 0; j < jn; ++j) {
    if (j + 1 < jn)
      asm volatile("s_waitcnt vmcnt(8)" ::: "memory");
    else
      asm volatile("s_waitcnt vmcnt(0)" ::: "memory");
    __builtin_amdgcn_s_barrier();
    const int bfr = j & 1;
    const unsigned short* Kb = Ks[bfr];
    const unsigned short* Vb = Vs[bfr];

    if (j <= jlw) {
      const int kv0 = j << 6;
      f32x4 s[2][4];
#pragma unroll
      for (int mf = 0; mf < 2; ++mf)
#pragma unroll
        for (int nf = 0; nf < 4; ++nf) s[mf][nf] = (f32x4){0.f, 0.f, 0.f, 0.f};
#pragma unroll
      for (int kk = 0; kk < 4; ++kk) {
        bf16x8 kf[4];
#pragma unroll
        for (int nf = 0; nf < 4; ++nf) {
          int rr = nf * 16 + ln;
          kf[nf] = *(const bf16x8*)
              &Kb[rr * 128 + (((kk * 64 + g * 16) ^ ((rr & 7) << 4)) >> 1)];
        }
#pragma unroll
        for (int mf = 0; mf < 2; ++mf)
#pragma unroll
          for (int nf = 0; nf < 4; ++nf)
            s[mf][nf] = mfma_bf16(qv[mf][kk], kf[nf], s[mf][nf]);
      }

      if (j == jlw) {
#pragma unroll
        for (int mf = 0; mf < 2; ++mf)
#pragma unroll
          for (int nf = 0; nf < 4; ++nf)
#pragma unroll
            for (int r = 0; r < 4; ++r)
              if (kv0 + nf * 16 + ln > Q0w + mf * 16 + g * 4 + r)
                s[mf][nf][r] = -3e38f;
      }

      // in-lane (partial) row max over this lane's 4 cols
      float mxl[2][4];
#pragma unroll
      for (int mf = 0; mf < 2; ++mf)
#pragma unroll
        for (int r = 0; r < 4; ++r)
          mxl[mf][r] = fmaxf(fmaxf(s[mf][0][r], s[mf][1][r]),
                             fmaxf(s[mf][2][r], s[mf][3][r]));

      // lazy defer-max (T13): __any over partial maxes is an equivalent trigger
      float dm = 0.f;
#pragma unroll
      for (int mf = 0; mf < 2; ++mf)
#pragma unroll
        for (int r = 0; r < 4; ++r) dm = fmaxf(dm, mxl[mf][r] - mrun[mf][r]);
      if (__any(dm > 11.5416f)) {   // exp2(11.5416) == e^8
#pragma unroll
        for (int mf = 0; mf < 2; ++mf)
#pragma unroll
          for (int r = 0; r < 4; ++r) {
            float m0 = mxl[mf][r];
            m0 = fmaxf(m0, __shfl_xor(m0, 1));
            m0 = fmaxf(m0, __shfl_xor(m0, 2));
            m0 = fmaxf(m0, __shfl_xor(m0, 4));
            m0 = fmaxf(m0, __shfl_xor(m0, 8));
            float mn = fmaxf(mrun[mf][r], m0);
            float al = exp2f(mrun[mf][r] - mn);
            mrun[mf][r] = mn;
            lpart[mf][r] *= al;
#pragma unroll
            for (int nf = 0; nf < 8; ++nf) o[mf][nf][r] *= al;
          }
      }

      // P = exp2(S - m), per-lane partial sums (reduced once at the end)
#pragma unroll
      for (int mf = 0; mf < 2; ++mf)
#pragma unroll
        for (int r = 0; r < 4; ++r) {
          const float m0 = mrun[mf][r];
          const int row_l = mf * 16 + g * 4 + r;
          float rs = 0.f;
#pragma unroll
          for (int nf = 0; nf < 4; ++nf) {
            float pv = exp2f(s[mf][nf][r] - m0);
            rs += pv;
            int byte = ((nf * 16 + ln) << 1) ^ ((row_l & 7) << 4);
            Pw[row_l * 64 + (byte >> 1)] = (__bf16)pv;
          }
          lpart[mf][r] += rs;
        }

      asm volatile("s_waitcnt lgkmcnt(0)" ::: "memory");
      __builtin_amdgcn_sched_barrier(0);

#pragma unroll
      for (int kk2 = 0; kk2 < 2; ++kk2) {
        bf16x8 pa[2];
#pragma unroll
        for (int mf = 0; mf < 2; ++mf) {
          int pr = mf * 16 + ln;
          int byte = (kk2 * 64 + g * 16) ^ ((pr & 7) << 4);
          pa[mf] = *(const bf16x8*)&Pw[pr * 64 + (byte >> 1)];
        }
#pragma unroll
        for (int nf2 = 0; nf2 < 8; ++nf2) {
          int dr = nf2 * 16 + ln;
          bf16x8 vf = *(const bf16x8*)
              &Vb[dr * 64 + (((kk2 * 64 + g * 16) ^ ((dr & 7) << 4)) >> 1)];
#pragma unroll
          for (int mf = 0; mf < 2; ++mf)
            o[mf][nf2] = mfma_bf16(pa[mf], vf, o[mf][nf2]);
        }
      }
    }

    __builtin_amdgcn_s_barrier();
    __builtin_amdgcn_sched_barrier(0);
    if (j + 2 < jn) STAGE_KV(j + 2, bfr);
  }
#undef STAGE_KV

  // final: one 16-lane sum reduce per row, then normalize + write y
  const int b = z >> 4, h = z & 15;
#pragma unroll
  for (int mf = 0; mf < 2; ++mf)
#pragma unroll
    for (int r = 0; r < 4; ++r) {
      float rs = lpart[mf][r];
      rs += __shfl_xor(rs, 1);
      rs += __shfl_xor(rs, 2);
      rs += __shfl_xor(rs, 4);
      rs += __shfl_xor(rs, 8);
      float inv = 1.f / rs;
      int t = Q0w + mf * 16 + g * 4 + r;
      size_t rb = ((size_t)b * 2048 + t) * 2048 + h * 128;
#pragma unroll
      for (int nf2 = 0; nf2 < 8; ++nf2)
        ybf[rb + nf2 * 16 + ln] = f2bf(o[mf][nf2][r] * inv);
    }
}

// ---------------------------------------------------------------------------
// Launch
// ---------------------------------------------------------------------------
extern "C" void kernel_launch(void* const* d_in, const int* in_sizes, int n_in,
                              void* d_out, int out_size, void* d_ws, size_t ws_size,
                              hipStream_t stream) {
  (void)in_sizes; (void)n_in; (void)out_size; (void)ws_size;
  const float* x      = (const float*)d_in[0];
  const float* W_attn = (const float*)d_in[1];
  const float* b_attn = (const float*)d_in[2];
  const float* W_proj = (const float*)d_in[3];
  const float* b_proj = (const float*)d_in[4];

  float* out   = (float*)d_out;                 // [8192][2048]
  float* out_k = out + 16777216;                // [64][2048][128]
  float* out_v = out + 33554432;                // [64][2048][128]

  char* ws = (char*)d_ws;
  unsigned short* q_bf  = (unsigned short*)(ws + 0);           // 33.5 MB
  unsigned short* k_bf  = (unsigned short*)(ws + 33554432);    // 33.5 MB
  unsigned short* vt_bf = (unsigned short*)(ws + 67108864);    // 33.5 MB
  unsigned short* x_bf  = (unsigned short*)(ws + 100663296);   // 33.5 MB (reused as y2d)
  unsigned short* y2d   = x_bf;                                // x_bf dead after GEMM1
  unsigned short* wt    = (unsigned short*)(ws + 134217728);   // 25.2 MB
  unsigned short* wpt   = (unsigned short*)(ws + 159383552);   // 8.4 MB
  float* cos_t = (float*)(ws + 167772160);                     // 0.5 MB
  float* sin_t = (float*)(ws + 168296448);                     // 0.5 MB

  prep_kernel<<<5632, 256, 0, stream>>>(x, x_bf, W_attn, wt, cos_t, sin_t);
  gemm_qkv_kernel<<<768, 512, 0, stream>>>(x_bf, wt, b_attn, cos_t, sin_t,
                                           out_k, out_v, q_bf, k_bf, vt_bf);
  attn_kernel<<<2048, 256, 0, stream>>>(q_bf, k_bf, vt_bf, y2d, W_proj, wpt);
  gemm_proj_kernel<<<256, 512, 0, stream>>>(y2d, wpt, b_proj, out);
}

// Round 19
// 405.282 us; speedup vs baseline: 1.0852x; 1.0037x over previous
//
#include <hip/hip_runtime.h>

// ---------------------------------------------------------------------------
// CausalSelfAttention on MI355X (gfx950), bf16 MFMA pipeline.
// Shapes: B=4, T=2048, C=2048, H=16, D=128. N_qkv=6144.
// d_out = [ out f32 (B,T,C) | k f32 (B,H,T,D) | v f32 (B,H,T,D) ]
// ---------------------------------------------------------------------------

typedef __attribute__((ext_vector_type(4))) float f32x4;
typedef __attribute__((ext_vector_type(8))) __bf16 bf16x8;
typedef __attribute__((ext_vector_type(4))) unsigned short us4;
typedef __attribute__((ext_vector_type(8))) unsigned short us8;

__device__ __forceinline__ unsigned short f2bf(float f) {
  unsigned u = __float_as_uint(f);
  u += 0x7FFFu + ((u >> 16) & 1u);   // round-to-nearest-even
  return (unsigned short)(u >> 16);
}

__device__ __forceinline__ void gl_lds16(const void* g, void* l) {
  __builtin_amdgcn_global_load_lds(
      (const __attribute__((address_space(1))) void*)g,
      (__attribute__((address_space(3))) void*)l, 16, 0, 0);
}

__device__ __forceinline__ f32x4 mfma_bf16(bf16x8 a, bf16x8 b, f32x4 c) {
  return __builtin_amdgcn_mfma_f32_16x16x32_bf16(a, b, c, 0, 0, 0);
}

// ---------------------------------------------------------------------------
// Fused prep kernel:
//   [0,2048)        conv_bf16 of x             (grid-stride, 8 float4/thread)
//   [2048,5120)     transpose W_attn (permuted) 96 x 32 tiles
//   [5120,5632)     rope cos/sin table
// (W_proj transpose rides in the attn launch -- consumed only by gemm_proj.)
// ---------------------------------------------------------------------------
__global__ __launch_bounds__(256) void prep_kernel(
    const float* __restrict__ x, unsigned short* __restrict__ x_bf,
    const float* __restrict__ W_attn, unsigned short* __restrict__ wt,
    float* __restrict__ cos_t, float* __restrict__ sin_t) {
  __shared__ unsigned short tile[64][68];
  const int bid = blockIdx.x;
  const int t = threadIdx.x;

  if (bid < 2048) {  // ---- conv_bf16 ----
    int idx = bid * 256 + t;
    for (; idx < 4194304; idx += 2048 * 256) {
      float4 v = ((const float4*)x)[idx];
      us4 o;
      o[0] = f2bf(v.x); o[1] = f2bf(v.y); o[2] = f2bf(v.z); o[3] = f2bf(v.w);
      ((us4*)x_bf)[idx] = o;
    }
    return;
  }
  if (bid >= 5120) {  // ---- rope table ----
    int idx = (bid - 5120) * 256 + t;
    int tt = idx >> 6, i = idx & 63;
    float freq = __expf(-(float)i * 0.14391156831212787f);  // 10000^(-i/64)
    float ang = (float)tt * freq;
    float s, c;
    sincosf(ang, &s, &c);
    cos_t[idx] = c;
    sin_t[idx] = s;
    return;
  }

  // ---- transpose W_attn (permuted) ----
  const int loc = bid - 2048;
  const int bx = loc % 96, by = loc / 96;
  const int c0 = bx * 64, r0 = by * 64;
  const int cq = t & 15, rr = t >> 4;
#pragma unroll
  for (int i = 0; i < 4; ++i) {
    int r = rr + i * 16;
    float4 v = *(const float4*)&W_attn[(size_t)(r0 + r) * 6144 + c0 + cq * 4];
    tile[r][cq * 4 + 0] = f2bf(v.x);
    tile[r][cq * 4 + 1] = f2bf(v.y);
    tile[r][cq * 4 + 2] = f2bf(v.z);
    tile[r][cq * 4 + 3] = f2bf(v.w);
  }
  __syncthreads();
#pragma unroll
  for (int ii = 0; ii < 4; ++ii) {
    int c = rr + ii * 16;
    int n = c0 + c;
    int np = n;
    if (n < 4096) {  // q/k sections: swap middle 32-blocks (RoPE pairing)
      int d = n & 127, blk = d >> 5;
      int dd = (blk == 1) ? d + 32 : (blk == 2) ? d - 32 : d;
      np = (n & ~127) | dd;
    }
    us4 o;
#pragma unroll
    for (int jj = 0; jj < 4; ++jj) o[jj] = tile[cq * 4 + jj][c];
    *(us4*)&wt[(size_t)np * 2048 + r0 + cq * 4] = o;
  }
}

// ---------------------------------------------------------------------------
// 256x256 8-wave GEMM engine, 4-phase LDS-minimal schedule (best measured).
// Wait soundness (vmcnt counts per-thread load ENTRIES; each STAGE = 2):
//  - entry: outstanding 8 = {A0,A0,B0,B0,B1,B1,A1,A1}; WAITV(2) confirms
//    oldest 6 = A0,B0,B1.
//  - mid: outstanding 6 = {A1,A1,nA0,nA0,nB0,nB0}; WAITV(4) confirms A1.
// vs r18: LDB2 split per-half -- ph1 issues only LDB(0)+LDA(0) (12 reads)
// so MF16(0,0) starts ~4 read-slots earlier; LDB(1) issues in ph2 right
// before its consumer MF16(0,1). bv[0,1]/bv[2,3] disjoint; buffer stable
// all tile; MF16(1,*) reuse regs still live. Sync/stage map unchanged.
// setprio(1) around MFMA clusters (removing it cost ~24us, r15 A/B).
// ---------------------------------------------------------------------------

#define BARR __builtin_amdgcn_s_barrier()
#define WAITV(N) asm volatile("s_waitcnt vmcnt(" #N ")" ::: "memory")

#define STAGE_A_HALF(BUF, T, H)                                                \
  do {                                                                         \
    const int k0_ = (T) * 64;                                                  \
    _Pragma("unroll") for (int i_ = 0; i_ < 2; ++i_) {                         \
      int c_ = i_ * 512 + tid;                                                 \
      int rp_ = c_ >> 3, s_ = c_ & 7;                                          \
      int row_ = (rp_ & 63) + (H) * 64 + (rp_ >> 6) * 128;                     \
      gl_lds16(Ag + (size_t)row_ * 2048 + k0_ + ((s_ ^ (row_ & 7)) << 3),      \
               &As[BUF][row_ * 64 + s_ * 8]);                                  \
    }                                                                          \
  } while (0)

#define STAGE_B_HALF(BUF, T, H)                                                \
  do {                                                                         \
    const int k0_ = (T) * 64;                                                  \
    _Pragma("unroll") for (int i_ = 0; i_ < 2; ++i_) {                         \
      int c_ = i_ * 512 + tid;                                                 \
      int rp_ = c_ >> 3, s_ = c_ & 7;                                          \
      int row_ = (rp_ & 31) + (H) * 32 + (rp_ >> 5) * 64;                      \
      gl_lds16(Bg + (size_t)row_ * 2048 + k0_ + ((s_ ^ (row_ & 7)) << 3),      \
               &Bs[BUF][row_ * 64 + s_ * 8]);                                  \
    }                                                                          \
  } while (0)

#define LDA(mh)                                                                \
  _Pragma("unroll") for (int m2_ = 0; m2_ < 4; ++m2_)                          \
  _Pragma("unroll") for (int kk_ = 0; kk_ < 2; ++kk_) {                        \
    int R_ = wm * 128 + (mh) * 64 + m2_ * 16 + ln;                             \
    av[m2_][kk_] = *(const bf16x8*)&Ab[R_ * 64 +                               \
        (((kk_ * 64 + g * 16) ^ ((R_ & 7) << 4)) >> 1)];                       \
  }

#define LDB(nh)                                                                \
  _Pragma("unroll") for (int n2_ = 0; n2_ < 2; ++n2_)                          \
  _Pragma("unroll") for (int kk_ = 0; kk_ < 2; ++kk_) {                        \
    int R_ = wn * 64 + (nh) * 32 + n2_ * 16 + ln;                              \
    bv[(nh) * 2 + n2_][kk_] = *(const bf16x8*)&Bb[R_ * 64 +                    \
        (((kk_ * 64 + g * 16) ^ ((R_ & 7) << 4)) >> 1)];                       \
  }

#define MF16(mh, nh)                                                           \
  do {                                                                         \
    __builtin_amdgcn_s_setprio(1);                                             \
    _Pragma("unroll") for (int m2_ = 0; m2_ < 4; ++m2_)                        \
    _Pragma("unroll") for (int n2_ = 0; n2_ < 2; ++n2_)                        \
    _Pragma("unroll") for (int kk_ = 0; kk_ < 2; ++kk_)                        \
      acc[(mh) * 4 + m2_][(nh) * 2 + n2_] = mfma_bf16(                         \
          av[m2_][kk_], bv[(nh) * 2 + n2_][kk_],                               \
          acc[(mh) * 4 + m2_][(nh) * 2 + n2_]);                                \
    __builtin_amdgcn_s_setprio(0);                                             \
  } while (0)

#define GEMM_ENGINE_4PH(NT)                                                    \
  STAGE_A_HALF(0, 0, 0); STAGE_B_HALF(0, 0, 0);                                \
  STAGE_B_HALF(0, 0, 1); STAGE_A_HALF(0, 0, 1);                                \
  for (int t = 0; t < (NT); ++t) {                                             \
    const int p_ = t & 1, q_ = p_ ^ 1;                                         \
    const unsigned short* Ab = &As[p_][0];                                     \
    const unsigned short* Bb = &Bs[p_][0];                                     \
    const bool pf_ = (t + 1 < (NT));                                           \
    WAITV(2);   /* entries: confirm oldest 6 = cur.{A0,B0,B1} */               \
    BARR;                                                                      \
    /* ph1: B-half0 + A-half0 reads (12); stage next.A0 */                     \
    LDB(0); LDA(0);                                                            \
    if (pf_) STAGE_A_HALF(q_, t + 1, 0);                                       \
    MF16(0, 0);                                                                \
    /* ph2: B-half1 reads (4); stage next.B0 */                                \
    LDB(1);                                                                    \
    if (pf_) STAGE_B_HALF(q_, t + 1, 0);                                       \
    MF16(0, 1);                                                                \
    if (pf_) { WAITV(4); } else { WAITV(0); }  /* confirm cur.A1 exactly */    \
    BARR;                                                                      \
    /* ph3: A-half1 reads; stage next.B1 */                                    \
    LDA(1);                                                                    \
    if (pf_) STAGE_B_HALF(q_, t + 1, 1);                                       \
    MF16(1, 0);                                                                \
    /* ph4: stage next.A1 */                                                   \
    if (pf_) STAGE_A_HALF(q_, t + 1, 1);                                       \
    MF16(1, 1);                                                                \
  }

// ---------------------------------------------------------------------------
// GEMM1: qkv = x @ W_attn + b_attn, fused RoPE epilogue (permuted q/k cols).
// q pre-scaled by (1/sqrt(D))*log2(e) (exp2-domain softmax). v-epilogue
// emits vt bf16 [z][D][T] via LDS transpose (coalesced 256B-segment writes).
// Grid 768; XCD x owns mtiles [4x,4x+4) x all 24 ntiles, n-fastest.
// ---------------------------------------------------------------------------
__global__ __launch_bounds__(512, 2) void gemm_qkv_kernel(
    const unsigned short* __restrict__ xbf, const unsigned short* __restrict__ wt,
    const float* __restrict__ bias, const float* __restrict__ cost,
    const float* __restrict__ sint, float* __restrict__ out_k,
    float* __restrict__ out_v, unsigned short* __restrict__ qbf,
    unsigned short* __restrict__ kbf, unsigned short* __restrict__ vtb) {
  __shared__ __attribute__((aligned(16))) unsigned short As[2][256 * 64];
  __shared__ __attribute__((aligned(16))) unsigned short Bs[2][256 * 64];
  const int tid = threadIdx.x;
  const int wid = tid >> 6, l = tid & 63, g = l >> 4, ln = l & 15;
  const int wm = wid >> 2, wn = wid & 3;
  const int xcd = blockIdx.x & 7, local = blockIdx.x >> 3;  // local in [0,96)
  const int mtile = xcd * 4 + (local & 3);
  const int ntile = local >> 2;
  const unsigned short* Ag = xbf + (size_t)(mtile * 256) * 2048;
  const unsigned short* Bg = wt + (size_t)(ntile * 256) * 2048;

  f32x4 acc[8][4];
#pragma unroll
  for (int i = 0; i < 8; ++i)
#pragma unroll
    for (int j = 0; j < 4; ++j) acc[i][j] = (f32x4){0.f, 0.f, 0.f, 0.f};
  bf16x8 av[4][2], bv[4][2];

  GEMM_ENGINE_4PH(32);

  // ---- epilogue ----
  const int colb = ntile * 256 + wn * 64;   // permuted col base of this wave
  const int p = colb >> 11;                 // block-uniform (ntile-determined)
  const int h = (colb >> 7) & 15;
  const int Mb = mtile * 256 + wm * 128;

  if (p == 2) {  // v: f32 out + bf16 V^T via LDS transpose
    __syncthreads();   // all waves done with main-loop LDS
    unsigned short* reg = (wid < 4) ? &As[0][0] + wid * 8192
                                    : &Bs[0][0] + (wid - 4) * 8192;  // 16KB/wave
    float bvv[4];
#pragma unroll
    for (int nf = 0; nf < 4; ++nf) bvv[nf] = bias[colb + nf * 16 + ln];
    const int dbase = (wn & 1) * 64;
#pragma unroll
    for (int mf = 0; mf < 8; ++mf) {
      int t0 = Mb + mf * 16 + g * 4;
      int bb = t0 >> 11, tt = t0 & 2047;
      size_t base = ((size_t)(bb * 16 + h) * 2048 + tt) * 128;
#pragma unroll
      for (int nf = 0; nf < 4; ++nf) {
        int dl = nf * 16 + ln;                 // wave-local dim 0..63
        us4 pack;
#pragma unroll
        for (int r = 0; r < 4; ++r) {
          float val = acc[mf][nf][r] + bvv[nf];
          out_v[base + (size_t)r * 128 + dbase + dl] = val;
          pack[r] = f2bf(val);
        }
        int byt = (mf * 32 + g * 8) ^ ((dl & 7) << 4);   // swizzled 8B slot
        *(us4*)&reg[dl * 128 + (byt >> 1)] = pack;       // LDS[dl][t] transposed
      }
    }
    asm volatile("s_waitcnt lgkmcnt(0)" ::: "memory");   // wave-private region
    __builtin_amdgcn_sched_barrier(0);
    const size_t vtz = (size_t)((Mb >> 11) * 16 + h) * (128 * 2048);
    const int tbase = (Mb & 2047);           // wave's 128 tokens (wm in Mb)
#pragma unroll
    for (int it = 0; it < 16; ++it) {
      int dl = it * 4 + (l >> 4);
      int byt = ((l & 15) * 16) ^ ((dl & 7) << 4);
      us8 v8 = *(const us8*)&reg[dl * 128 + (byt >> 1)];
      *(us8*)&vtb[vtz + (size_t)(dbase + dl) * 2048 + tbase + (l & 15) * 8] = v8;
    }
  } else {  // q (p==0) or k (p==1): RoPE; partners are acc[.][nf] / acc[.][nf+2]
    // q additionally scaled by 1/sqrt(128) * log2(e) for exp2-domain softmax
    const float sc2 = 0.12751743681128098f;
    const int half32 = (wn & 1) * 32;
    float blo[2], bhi[2];
#pragma unroll
    for (int nf = 0; nf < 2; ++nf) {
      int d_lo = half32 + nf * 16 + ln;
      blo[nf] = bias[p * 2048 + h * 128 + d_lo];
      bhi[nf] = bias[p * 2048 + h * 128 + d_lo + 64];
    }
#pragma unroll
    for (int mf = 0; mf < 8; ++mf)
#pragma unroll
      for (int r = 0; r < 4; ++r) {
        int m = Mb + mf * 16 + g * 4 + r;
        int b = m >> 11, t = m & 2047;
        size_t base = ((size_t)(b * 16 + h) * 2048 + t) * 128;
#pragma unroll
        for (int nf = 0; nf < 2; ++nf) {
          int d_lo = half32 + nf * 16 + ln;
          float cv = cost[t * 64 + d_lo], sv = sint[t * 64 + d_lo];
          float a = acc[mf][nf][r] + blo[nf];
          float bq = acc[mf][nf + 2][r] + bhi[nf];
          float lo = a * cv - bq * sv;
          float hi = bq * cv + a * sv;
          if (p == 0) {
            qbf[base + d_lo] = f2bf(lo * sc2);
            qbf[base + d_lo + 64] = f2bf(hi * sc2);
          } else {
            out_k[base + d_lo] = lo;
            out_k[base + d_lo + 64] = hi;
            kbf[base + d_lo] = f2bf(lo);
            kbf[base + d_lo + 64] = f2bf(hi);
          }
        }
      }
  }
}

// ---------------------------------------------------------------------------
// GEMM2: out = y @ W_proj + b_proj (f32). Grid 256; XCD x owns mtiles
// [4x,4x+4) x all 8 ntiles, n-fastest.
// ---------------------------------------------------------------------------
__global__ __launch_bounds__(512, 2) void gemm_proj_kernel(
    const unsigned short* __restrict__ ybf, const unsigned short* __restrict__ wpt,
    const float* __restrict__ bias, float* __restrict__ out) {
  __shared__ __attribute__((aligned(16))) unsigned short As[2][256 * 64];
  __shared__ __attribute__((aligned(16))) unsigned short Bs[2][256 * 64];
  const int tid = threadIdx.x;
  const int wid = tid >> 6, l = tid & 63, g = l >> 4, ln = l & 15;
  const int wm = wid >> 2, wn = wid & 3;
  const int xcd = blockIdx.x & 7, local = blockIdx.x >> 3;  // local in [0,32)
  const int mtile = xcd * 4 + (local & 3);
  const int ntile = local >> 2;
  const unsigned short* Ag = ybf + (size_t)(mtile * 256) * 2048;
  const unsigned short* Bg = wpt + (size_t)(ntile * 256) * 2048;

  f32x4 acc[8][4];
#pragma unroll
  for (int i = 0; i < 8; ++i)
#pragma unroll
    for (int j = 0; j < 4; ++j) acc[i][j] = (f32x4){0.f, 0.f, 0.f, 0.f};
  bf16x8 av[4][2], bv[4][2];

  GEMM_ENGINE_4PH(32);

  const int n0 = ntile * 256 + wn * 64;
  const int Mb = mtile * 256 + wm * 128;
  float bvv[4];
#pragma unroll
  for (int nf = 0; nf < 4; ++nf) bvv[nf] = bias[n0 + nf * 16 + ln];
#pragma unroll
  for (int mf = 0; mf < 8; ++mf)
#pragma unroll
    for (int r = 0; r < 4; ++r) {
      int m = Mb + mf * 16 + g * 4 + r;
      size_t rb = (size_t)m * 2048 + n0;
#pragma unroll
      for (int nf = 0; nf < 4; ++nf)
        out[rb + nf * 16 + ln] = acc[mf][nf][r] + bvv[nf];
    }
}

// ---------------------------------------------------------------------------
// Flash attention (unchanged) + fused W_proj transpose (blocks [1024,2048)).
// ---------------------------------------------------------------------------
__global__ __launch_bounds__(256, 2) void attn_kernel(
    const unsigned short* __restrict__ qbf, const unsigned short* __restrict__ kbf,
    const unsigned short* __restrict__ vtbf, unsigned short* __restrict__ ybf,
    const float* __restrict__ W_proj, unsigned short* __restrict__ wpt) {
  __shared__ __attribute__((aligned(16))) unsigned short Ks[2][64 * 128];
  __shared__ __attribute__((aligned(16))) unsigned short Vs[2][128 * 64];
  __shared__ __attribute__((aligned(16))) __bf16 Ps[4][32 * 64];
  const int tid = threadIdx.x;

  if (blockIdx.x >= 1024) {  // ---- W_proj transpose (reuses Ks[0] as tile) ----
    unsigned short (*tile)[68] = (unsigned short(*)[68])&Ks[0][0];
    const int loc = blockIdx.x - 1024;
    const int bx = loc & 31, by = loc >> 5;
    const int c0 = bx * 64, r0 = by * 64;
    const int cq = tid & 15, rr = tid >> 4;
#pragma unroll
    for (int i = 0; i < 4; ++i) {
      int r = rr + i * 16;
      float4 v = *(const float4*)&W_proj[(size_t)(r0 + r) * 2048 + c0 + cq * 4];
      tile[r][cq * 4 + 0] = f2bf(v.x);
      tile[r][cq * 4 + 1] = f2bf(v.y);
      tile[r][cq * 4 + 2] = f2bf(v.z);
      tile[r][cq * 4 + 3] = f2bf(v.w);
    }
    __syncthreads();
#pragma unroll
    for (int ii = 0; ii < 4; ++ii) {
      int c = rr + ii * 16;
      us4 o;
#pragma unroll
      for (int jj = 0; jj < 4; ++jj) o[jj] = tile[cq * 4 + jj][c];
      *(us4*)&wpt[(size_t)(c0 + c) * 2048 + r0 + cq * 4] = o;
    }
    return;
  }

  const int w = tid >> 6, l = tid & 63, g = l >> 4, ln = l & 15;
  const int bid = blockIdx.x;
  const int z = (bid & 7) * 8 + ((bid >> 3) & 7);
  const int qp = 15 - (bid >> 6);
  const size_t zo = (size_t)z * (2048 * 128);
  const size_t zv = (size_t)z * (128 * 2048);
  const int Q0w = qp * 128 + w * 32;
  const int jn = 2 * qp + 2;
  const int jlw = 2 * qp + (w >> 1);
  __bf16* Pw = Ps[w];

  bf16x8 qv[2][4];
#pragma unroll
  for (int mf = 0; mf < 2; ++mf)
#pragma unroll
    for (int kk = 0; kk < 4; ++kk)
      qv[mf][kk] = *(const bf16x8*)
          &qbf[zo + (size_t)(Q0w + mf * 16 + ln) * 128 + kk * 32 + g * 8];

  f32x4 o[2][8];
#pragma unroll
  for (int mf = 0; mf < 2; ++mf)
#pragma unroll
    for (int nf = 0; nf < 8; ++nf) o[mf][nf] = (f32x4){0.f, 0.f, 0.f, 0.f};
  float mrun[2][4], lpart[2][4];
#pragma unroll
  for (int mf = 0; mf < 2; ++mf)
#pragma unroll
    for (int r = 0; r < 4; ++r) { mrun[mf][r] = -3e38f; lpart[mf][r] = 0.f; }

#define STAGE_KV(J, B)                                                         \
  do {                                                                         \
    const int kv0_ = (J) << 6;                                                 \
    _Pragma("unroll") for (int i_ = 0; i_ < 4; ++i_) {                         \
      int c_ = i_ * 256 + tid;                                                 \
      int r_ = c_ >> 4, s_ = c_ & 15;                                          \
      gl_lds16(kbf + zo + (size_t)(kv0_ + r_) * 128 +                          \
                   (((s_ * 16) ^ ((r_ & 7) << 4)) >> 1),                       \
               &Ks[B][c_ * 8]);                                                \
    }                                                                          \
    _Pragma("unroll") for (int i_ = 0; i_ < 4; ++i_) {                         \
      int c_ = i_ * 256 + tid;                                                 \
      int d_ = c_ >> 3, s_ = c_ & 7;                                           \
      gl_lds16(vtbf + zv + (size_t)d_ * 2048 + kv0_ +                          \
                   (((s_ * 16) ^ ((d_ & 7) << 4)) >> 1),                       \
               &Vs[B][c_ * 8]);                                                \
    }                                                                          \
  } while (0)

  STAGE_KV(0, 0);
  STAGE_KV(1, 1);

  for (int j = 0; j < jn; ++j) {
    if (j + 1 < jn)
      asm volatile("s_waitcnt vmcnt(8)" ::: "memory");
    else
      asm volatile("s_waitcnt vmcnt(0)" ::: "memory");
    __builtin_amdgcn_s_barrier();
    const int bfr = j & 1;
    const unsigned short* Kb = Ks[bfr];
    const unsigned short* Vb = Vs[bfr];

    if (j <= jlw) {
      const int kv0 = j << 6;
      f32x4 s[2][4];
#pragma unroll
      for (int mf = 0; mf < 2; ++mf)
#pragma unroll
        for (int nf = 0; nf < 4; ++nf) s[mf][nf] = (f32x4){0.f, 0.f, 0.f, 0.f};
#pragma unroll
      for (int kk = 0; kk < 4; ++kk) {
        bf16x8 kf[4];
#pragma unroll
        for (int nf = 0; nf < 4; ++nf) {
          int rr = nf * 16 + ln;
          kf[nf] = *(const bf16x8*)
              &Kb[rr * 128 + (((kk * 64 + g * 16) ^ ((rr & 7) << 4)) >> 1)];
        }
#pragma unroll
        for (int mf = 0; mf < 2; ++mf)
#pragma unroll
          for (int nf = 0; nf < 4; ++nf)
            s[mf][nf] = mfma_bf16(qv[mf][kk], kf[nf], s[mf][nf]);
      }

      if (j == jlw) {
#pragma unroll
        for (int mf = 0; mf < 2; ++mf)
#pragma unroll
          for (int nf = 0; nf < 4; ++nf)
#pragma unroll
            for (int r = 0; r < 4; ++r)
              if (kv0 + nf * 16 + ln > Q0w + mf * 16 + g * 4 + r)
                s[mf][nf][r] = -3e38f;
      }

      // in-lane (partial) row max over this lane's 4 cols
      float mxl[2][4];
#pragma unroll
      for (int mf = 0; mf < 2; ++mf)
#pragma unroll
        for (int r = 0; r < 4; ++r)
          mxl[mf][r] = fmaxf(fmaxf(s[mf][0][r], s[mf][1][r]),
                             fmaxf(s[mf][2][r], s[mf][3][r]));

      // lazy defer-max (T13): __any over partial maxes is an equivalent trigger
      float dm = 0.f;
#pragma unroll
      for (int mf = 0; mf < 2; ++mf)
#pragma unroll
        for (int r = 0; r < 4; ++r) dm = fmaxf(dm, mxl[mf][r] - mrun[mf][r]);
      if (__any(dm > 11.5416f)) {   // exp2(11.5416) == e^8
#pragma unroll
        for (int mf = 0; mf < 2; ++mf)
#pragma unroll
          for (int r = 0; r < 4; ++r) {
            float m0 = mxl[mf][r];
            m0 = fmaxf(m0, __shfl_xor(m0, 1));
            m0 = fmaxf(m0, __shfl_xor(m0, 2));
            m0 = fmaxf(m0, __shfl_xor(m0, 4));
            m0 = fmaxf(m0, __shfl_xor(m0, 8));
            float mn = fmaxf(mrun[mf][r], m0);
            float al = exp2f(mrun[mf][r] - mn);
            mrun[mf][r] = mn;
            lpart[mf][r] *= al;
#pragma unroll
            for (int nf = 0; nf < 8; ++nf) o[mf][nf][r] *= al;
          }
      }

      // P = exp2(S - m), per-lane partial sums (reduced once at the end)
#pragma unroll
      for (int mf = 0; mf < 2; ++mf)
#pragma unroll
        for (int r = 0; r < 4; ++r) {
          const float m0 = mrun[mf][r];
          const int row_l = mf * 16 + g * 4 + r;
          float rs = 0.f;
#pragma unroll
          for (int nf = 0; nf < 4; ++nf) {
            float pv = exp2f(s[mf][nf][r] - m0);
            rs += pv;
            int byte = ((nf * 16 + ln) << 1) ^ ((row_l & 7) << 4);
            Pw[row_l * 64 + (byte >> 1)] = (__bf16)pv;
          }
          lpart[mf][r] += rs;
        }

      asm volatile("s_waitcnt lgkmcnt(0)" ::: "memory");
      __builtin_amdgcn_sched_barrier(0);

#pragma unroll
      for (int kk2 = 0; kk2 < 2; ++kk2) {
        bf16x8 pa[2];
#pragma unroll
        for (int mf = 0; mf < 2; ++mf) {
          int pr = mf * 16 + ln;
          int byte = (kk2 * 64 + g * 16) ^ ((pr & 7) << 4);
          pa[mf] = *(const bf16x8*)&Pw[pr * 64 + (byte >> 1)];
        }
#pragma unroll
        for (int nf2 = 0; nf2 < 8; ++nf2) {
          int dr = nf2 * 16 + ln;
          bf16x8 vf = *(const bf16x8*)
              &Vb[dr * 64 + (((kk2 * 64 + g * 16) ^ ((dr & 7) << 4)) >> 1)];
#pragma unroll
          for (int mf = 0; mf < 2; ++mf)
            o[mf][nf2] = mfma_bf16(pa[mf], vf, o[mf][nf2]);
        }
      }
    }

    __builtin_amdgcn_s_barrier();
    __builtin_amdgcn_sched_barrier(0);
    if (j + 2 < jn) STAGE_KV(j + 2, bfr);
  }
#undef STAGE_KV

  // final: one 16-lane sum reduce per row, then normalize + write y
  const int b = z >> 4, h = z & 15;
#pragma unroll
  for (int mf = 0; mf < 2; ++mf)
#pragma unroll
    for (int r = 0; r < 4; ++r) {
      float rs = lpart[mf][r];
      rs += __shfl_xor(rs, 1);
      rs += __shfl_xor(rs, 2);
      rs += __shfl_xor(rs, 4);
      rs += __shfl_xor(rs, 8);
      float inv = 1.f / rs;
      int t = Q0w + mf * 16 + g * 4 + r;
      size_t rb = ((size_t)b * 2048 + t) * 2048 + h * 128;
#pragma unroll
      for (int nf2 = 0; nf2 < 8; ++nf2)
        ybf[rb + nf2 * 16 + ln] = f2bf(o[mf][nf2][r] * inv);
    }
}

// ---------------------------------------------------------------------------
// Launch
// ---------------------------------------------------------------------------
extern "C" void kernel_launch(void* const* d_in, const int* in_sizes, int n_in,
                              void* d_out, int out_size, void* d_ws, size_t ws_size,
                              hipStream_t stream) {
  (void)in_sizes; (void)n_in; (void)out_size; (void)ws_size;
  const float* x      = (const float*)d_in[0];
  const float* W_attn = (const float*)d_in[1];
  const float* b_attn = (const float*)d_in[2];
  const float* W_proj = (const float*)d_in[3];
  const float* b_proj = (const float*)d_in[4];

  float* out   = (float*)d_out;                 // [8192][2048]
  float* out_k = out + 16777216;                // [64][2048][128]
  float* out_v = out + 33554432;                // [64][2048][128]

  char* ws = (char*)d_ws;
  unsigned short* q_bf  = (unsigned short*)(ws + 0);           // 33.5 MB
  unsigned short* k_bf  = (unsigned short*)(ws + 33554432);    // 33.5 MB
  unsigned short* vt_bf = (unsigned short*)(ws + 67108864);    // 33.5 MB
  unsigned short* x_bf  = (unsigned short*)(ws + 100663296);   // 33.5 MB (reused as y2d)
  unsigned short* y2d   = x_bf;                                // x_bf dead after GEMM1
  unsigned short* wt    = (unsigned short*)(ws + 134217728);   // 25.2 MB
  unsigned short* wpt   = (unsigned short*)(ws + 159383552);   // 8.4 MB
  float* cos_t = (float*)(ws + 167772160);                     // 0.5 MB
  float* sin_t = (float*)(ws + 168296448);                     // 0.5 MB

  prep_kernel<<<5632, 256, 0, stream>>>(x, x_bf, W_attn, wt, cos_t, sin_t);
  gemm_qkv_kernel<<<768, 512, 0, stream>>>(x_bf, wt, b_attn, cos_t, sin_t,
                                           out_k, out_v, q_bf, k_bf, vt_bf);
  attn_kernel<<<2048, 256, 0, stream>>>(q_bf, k_bf, vt_bf, y2d, W_proj, wpt);
  gemm_proj_kernel<<<256, 512, 0, stream>>>(y2d, wpt, b_proj, out);
}